// Round 14
// baseline (261.111 us; speedup 1.0000x reference)
//
#include <hip/hip_runtime.h>
#include <hip/hip_bf16.h>
#include <math.h>

#define THREADS 256

typedef __bf16 bf16_t;
typedef __bf16 bf16x8 __attribute__((ext_vector_type(8)));
typedef float f32x4 __attribute__((ext_vector_type(4)));

__device__ __forceinline__ float sigmoidf_(float x) { return 1.f / (1.f + expf(-x)); }

__device__ __forceinline__ void gload_lds16(const void* g, void* l) {
    __builtin_amdgcn_global_load_lds((const __attribute__((address_space(1))) void*)g,
                                     (__attribute__((address_space(3))) void*)l, 16, 0, 0);
}

__device__ __forceinline__ bf16x8 cvt8(float4 a, float4 b) {
    bf16x8 v;
    v[0] = (bf16_t)a.x; v[1] = (bf16_t)a.y; v[2] = (bf16_t)a.z; v[3] = (bf16_t)a.w;
    v[4] = (bf16_t)b.x; v[5] = (bf16_t)b.y; v[6] = (bf16_t)b.z; v[7] = (bf16_t)b.w;
    return v;
}

// ------------------------------------------------------------------
// prep_all: merged weight prep.
// [0,T1): WbfT [256][288], WqT [128][384], bpn[256], bpq[128].
// [T1,..): BTg [768][256], bgru, cnt zero, AG pad zero.
// ------------------------------------------------------------------
__global__ void prep_all(const float* __restrict__ W_key, const float* __restrict__ W_val,
                         const float* __restrict__ W_q, const float* __restrict__ b_key,
                         const float* __restrict__ b_val, const float* __restrict__ b_q,
                         bf16_t* __restrict__ WbfT, bf16_t* __restrict__ WqT,
                         float* __restrict__ bpn, float* __restrict__ bpq,
                         const float* __restrict__ W_ih, const float* __restrict__ W_hh,
                         const float* __restrict__ b_ih, const float* __restrict__ b_hh,
                         bf16_t* __restrict__ BTg, float* __restrict__ bgru,
                         int* __restrict__ cnt, int twoP,
                         bf16_t* __restrict__ AG, int padStart, int padElems)
{
    int i0 = blockIdx.x * THREADS + threadIdx.x;
    const int NW = 256 * 288, NQ = 128 * 384;
    const int T1 = NW + NQ + 256 + 128;
    if (i0 < T1) {
        int i = i0;
        if (i < NW) {
            int c = i / 288, k = i - c * 288;
            float v = 0.f;
            if (k < 283) {
                if (c < 100) v = W_key[k * 100 + c];
                else if (c >= 128 && c < 256) v = W_val[k * 128 + (c - 128)];
            }
            WbfT[i] = (bf16_t)v;
        } else if (i < NW + NQ) {
            int j = i - NW;
            int c = j / 384, k = j - c * 384;
            WqT[j] = (bf16_t)((c < 100) ? W_q[k * 100 + c] : 0.f);
        } else if (i < NW + NQ + 256) {
            int c = i - NW - NQ;
            bpn[c] = (c < 100) ? b_key[c] : ((c >= 128 && c < 256) ? b_val[c - 128] : 0.f);
        } else {
            int c = i - NW - NQ - 256;
            bpq[c] = (c < 100) ? b_q[c] : 0.f;
        }
        return;
    }
    int i = i0 - T1;
    const int NG = 768 * 256;
    if (i < NG) {
        int c = i >> 8, k = i & 255;
        float v = 0.f;
        if (c < 384) { if (k < 128) v = W_ih[k * 384 + c]; }
        else         { if (k >= 128) v = W_hh[(k - 128) * 384 + (c - 384)]; }
        BTg[i] = (bf16_t)v;
    } else if (i < NG + 768) {
        int c = i - NG;
        bgru[c] = (c < 384) ? b_ih[c] : b_hh[c - 384];
    } else if (i < NG + 768 + twoP) {
        cnt[i - NG - 768] = 0;
    } else if (i < NG + 768 + twoP + padElems) {
        int j = i - NG - 768 - twoP;
        AG[(size_t)padStart * 256 + j] = (bf16_t)0.f;
    }
}

// skip features -> skipb bf16 [Mpad,32] (27 real + 5 zero; pad rows zero)
__global__ void skip_kernel(const float* __restrict__ energy, const float* __restrict__ eta,
                            const float* __restrict__ phi, const float* __restrict__ layer,
                            const float* __restrict__ eta_l, const float* __restrict__ phi_l,
                            const float* __restrict__ ene_l, const float* __restrict__ track,
                            bf16_t* __restrict__ skipb, int N_, int Mpad)
{
    int n = blockIdx.x * THREADS + threadIdx.x;
    if (n >= Mpad) return;
    float o[32];
#pragma unroll
    for (int j = 0; j < 32; ++j) o[j] = 0.f;
    if (n < N_) {
        o[0] = (logf(energy[n]) - 4.0f) * 0.5f;
        o[1] = eta[n] * (1.f / 1.5f);
        o[2] = phi[n];
        o[3] = layer[n];
#pragma unroll
        for (int j = 0; j < 6; ++j) o[4 + j]  = eta_l[n * 6 + j] * (1.f / 1.5f);
#pragma unroll
        for (int j = 0; j < 6; ++j) o[10 + j] = phi_l[n * 6 + j];
#pragma unroll
        for (int j = 0; j < 6; ++j) o[16 + j] = ene_l[n * 6 + j];
#pragma unroll
        for (int j = 0; j < 5; ++j) o[22 + j] = track[n * 5 + j];
    }
    bf16_t* dst = skipb + (size_t)n * 32;
#pragma unroll
    for (int g = 0; g < 4; ++g) {
        bf16x8 v;
#pragma unroll
        for (int j = 0; j < 8; ++j) v[j] = (bf16_t)o[g * 8 + j];
        *(bf16x8*)(dst + g * 8) = v;
    }
}

// ------------------------------------------------------------------
// kv_gemm1w: SINGLE-WAVE workgroups (64 thr), 32x64 tile, 6KB LDS.
// __syncthreads in a 1-wave block = vmcnt drain only (no cross-wave
// lockstep) -> up to 16 independent streams/CU vs ~3.5 for the 4-wave
// barrier-locked r8 structure. Same staging shapes & fragment math.
// ------------------------------------------------------------------
__global__ __launch_bounds__(64) void kv_gemm1w(
    const float* __restrict__ nh, const bf16_t* __restrict__ skipb,
    const bf16_t* __restrict__ BT, const float* __restrict__ bias,
    bf16_t* __restrict__ KVb, int N_)
{
    __shared__ short As[32 * 32];   // [row][k] 2 KB
    __shared__ short Bs[64 * 32];   // [col][k] 4 KB
    int lane = threadIdx.x;
    int la = lane & 15, hi = lane >> 4;
    int row0 = blockIdx.x * 32;
    int col0 = blockIdx.y * 64;

    // A chunks: 128 x 16B; lane handles c = lane, lane+64 (row=c>>2, ko=(c&3)*8)
    const int ca0 = lane, ca1 = lane + 64;
    const int ra0 = ca0 >> 2, ko0 = (ca0 & 3) * 8;
    const int ra1 = ca1 >> 2, ko1 = (ca1 & 3) * 8;
    // B chunks: 256 x 16B; lane handles lane + {0,64,128,192}
    f32x4 zero4 = {0.f, 0.f, 0.f, 0.f};
    f32x4 acc[2][4];
#pragma unroll
    for (int i = 0; i < 2; ++i)
#pragma unroll
        for (int j = 0; j < 4; ++j) acc[i][j] = zero4;

    for (int kt = 0; kt < 288; kt += 32) {
        if (kt < 256) {  // fp32 A -> cvt -> ds_write (kt wave-uniform)
            int g0 = row0 + ra0, g1 = row0 + ra1;
            bf16x8 v0 = {}, v1 = {};
            if (g0 < N_) {
                const float* s = nh + (size_t)g0 * 256 + kt + ko0;
                v0 = cvt8(*(const float4*)s, *(const float4*)(s + 4));
            }
            if (g1 < N_) {
                const float* s = nh + (size_t)g1 * 256 + kt + ko1;
                v1 = cvt8(*(const float4*)s, *(const float4*)(s + 4));
            }
            *(bf16x8*)(As + (size_t)ca0 * 8) = v0;
            *(bf16x8*)(As + (size_t)ca1 * 8) = v1;
        } else {         // skip tail bf16 (pad rows pre-zeroed)
            gload_lds16(skipb + (size_t)(row0 + ra0) * 32 + ko0, As + (size_t)ca0 * 8);
            gload_lds16(skipb + (size_t)(row0 + ra1) * 32 + ko1, As + (size_t)ca1 * 8);
        }
#pragma unroll
        for (int q = 0; q < 4; ++q) {
            int c = lane + q * 64;
            int rb = c >> 2, kb = (c & 3) * 8;
            gload_lds16(BT + (size_t)(col0 + rb) * 288 + kt + kb, Bs + (size_t)c * 8);
        }
        __syncthreads();
        bf16x8 a[2], b[4];
#pragma unroll
        for (int i = 0; i < 2; ++i)
            a[i] = *(const bf16x8*)(As + (i * 16 + la) * 32 + hi * 8);
#pragma unroll
        for (int j = 0; j < 4; ++j)
            b[j] = *(const bf16x8*)(Bs + (j * 16 + la) * 32 + hi * 8);
#pragma unroll
        for (int i = 0; i < 2; ++i)
#pragma unroll
            for (int j = 0; j < 4; ++j)
                acc[i][j] = __builtin_amdgcn_mfma_f32_16x16x32_bf16(a[i], b[j], acc[i][j], 0, 0, 0);
        __syncthreads();
    }

#pragma unroll
    for (int j = 0; j < 4; ++j) {
        int col = col0 + j * 16 + la;
        float bb = bias[col];
#pragma unroll
        for (int i = 0; i < 2; ++i) {
#pragma unroll
            for (int r = 0; r < 4; ++r) {
                int row = row0 + i * 16 + hi * 4 + r;
                KVb[(size_t)row * 256 + col] = (bf16_t)(acc[i][j][r] + bb);
            }
        }
    }
}

// ------------------------------------------------------------------
// bf16 MFMA GEMM (modes 1-2): 64x128 tile, BK=32, 4 waves, r8 structure.
// MODE 1: A = ph fp32 [.,128] | grep fp32 [.,256]; K=384; out Qb bf16
// MODE 2: A bf16 stride K; fp32 out ldc=768 (GRU gi|gh)
// ------------------------------------------------------------------
template <int MODE>
__global__ __launch_bounds__(256) void mfma_gemm(
    const void* __restrict__ A0, const void* __restrict__ A1,
    const bf16_t* __restrict__ BT, const float* __restrict__ bias,
    void* __restrict__ out0v, int K, int Nrows)
{
    __shared__ short AsS[64 * 32];
    __shared__ short BsS[128 * 32];
    int tid = threadIdx.x;
    int lane = tid & 63, w = tid >> 6;
    int la = lane & 15, hi = lane >> 4;
    int m0 = (w & 1) * 32, n0 = (w >> 1) * 64;
    int row0 = blockIdx.y * 64, col0 = blockIdx.x * 128;

    f32x4 zero4 = {0.f, 0.f, 0.f, 0.f};
    f32x4 acc[2][4];
#pragma unroll
    for (int i = 0; i < 2; ++i)
#pragma unroll
        for (int j = 0; j < 4; ++j) acc[i][j] = zero4;

    const int ra = tid >> 2, ka = (tid & 3) * 8;
    const int c1 = tid + 256;
    const int rb0 = tid >> 2, kb0 = (tid & 3) * 8;
    const int rb1 = c1 >> 2,  kb1 = (c1 & 3) * 8;

    for (int kt = 0; kt < K; kt += 32) {
        int gmA = row0 + ra;
        if (MODE == 1) {
            int gk = kt + ka;
            bf16x8 v = {};
            if (gmA < Nrows) {
                const float* s = (gk < 128) ? ((const float*)A0 + (size_t)gmA * 128 + gk)
                                            : ((const float*)A1 + (size_t)gmA * 256 + (gk - 128));
                v = cvt8(*(const float4*)s, *(const float4*)(s + 4));
            }
            *(bf16x8*)(AsS + (size_t)tid * 8) = v;
        } else {
            gload_lds16((const bf16_t*)A0 + (size_t)gmA * K + kt + ka,
                        AsS + (size_t)tid * 8);
        }
        gload_lds16(BT + (size_t)(col0 + rb0) * K + kt + kb0, BsS + (size_t)tid * 8);
        gload_lds16(BT + (size_t)(col0 + rb1) * K + kt + kb1, BsS + (size_t)c1 * 8);
        __syncthreads();
        bf16x8 a[2], b[4];
#pragma unroll
        for (int i = 0; i < 2; ++i)
            a[i] = *(const bf16x8*)(AsS + (m0 + i * 16 + la) * 32 + hi * 8);
#pragma unroll
        for (int j = 0; j < 4; ++j)
            b[j] = *(const bf16x8*)(BsS + (n0 + j * 16 + la) * 32 + hi * 8);
#pragma unroll
        for (int i = 0; i < 2; ++i)
#pragma unroll
            for (int j = 0; j < 4; ++j)
                acc[i][j] = __builtin_amdgcn_mfma_f32_16x16x32_bf16(a[i], b[j], acc[i][j], 0, 0, 0);
        __syncthreads();
    }

#pragma unroll
    for (int i = 0; i < 2; ++i) {
#pragma unroll
        for (int j = 0; j < 4; ++j) {
            int col = col0 + n0 + j * 16 + la;
            float bb = bias[col];
#pragma unroll
            for (int r = 0; r < 4; ++r) {
                int row = row0 + m0 + i * 16 + hi * 4 + r;
                float v = acc[i][j][r] + bb;
                if (MODE == 1) ((bf16_t*)out0v)[(size_t)row * 128 + col] = (bf16_t)v;
                else           ((float*)out0v)[(size_t)row * 768 + col] = v;
            }
        }
    }
}

// ------------------------------------------------------------------
// CSR build (cnt zeroed by prep_all)
// ------------------------------------------------------------------
__global__ void hist_kernel(const int* __restrict__ dst, int* __restrict__ cnt, int E_)
{
    int i = blockIdx.x * THREADS + threadIdx.x;
    if (i < E_) atomicAdd(&cnt[dst[i]], 1);
}

__global__ void scan_kernel(const int* __restrict__ cnt, int* __restrict__ offb, int P_)
{
    __shared__ int wsum[16];
    int tid = threadIdx.x;
    int lane = tid & 63, w = tid >> 6;
    int base = tid * 10;
    int c[10];
    int s = 0;
#pragma unroll
    for (int j = 0; j < 10; ++j) {
        int i = base + j;
        c[j] = (i < P_) ? cnt[i] : 0;
        s += c[j];
    }
    int pre = s;
    for (int o = 1; o < 64; o <<= 1) {
        int t = __shfl_up(pre, o);
        if (lane >= o) pre += t;
    }
    if (lane == 63) wsum[w] = pre;
    __syncthreads();
    if (w == 0 && lane < 16) {
        int v = wsum[lane];
        for (int o = 1; o < 16; o <<= 1) {
            int t = __shfl_up(v, o, 16);
            if (lane >= o) v += t;
        }
        wsum[lane] = v;
    }
    __syncthreads();
    int waveoff = (w == 0) ? 0 : wsum[w - 1];
    int run = waveoff + pre - s;
#pragma unroll
    for (int j = 0; j < 10; ++j) {
        int i = base + j;
        if (i <= P_) offb[i] = run;
        run += c[j];
    }
}

__global__ void fill_src_kernel(const int* __restrict__ dst, const int* __restrict__ src,
                                const int* __restrict__ offb, int* __restrict__ cur,
                                int* __restrict__ csrc, int E_)
{
    int i = blockIdx.x * THREADS + threadIdx.x;
    if (i < E_) {
        int d = dst[i];
        int pos = atomicAdd(&cur[d], 1);
        csrc[offb[d] + pos] = src[i];
    }
}

// ------------------------------------------------------------------
// fused attention + gather + rms/sigmoid gate (unchanged from r8)
// ------------------------------------------------------------------
__global__ __launch_bounds__(256) void edge_kernel(
    const int* __restrict__ offb, const int* __restrict__ csrc,
    const bf16_t* __restrict__ KVb, const bf16_t* __restrict__ Qb,
    const float* __restrict__ ph, const float* __restrict__ rms_w,
    const float* __restrict__ lin_w, bf16_t* __restrict__ AG, int P_)
{
    int tid = threadIdx.x;
    int p = blockIdx.x * 4 + (tid >> 6);
    if (p >= P_) return;
    int lane = tid & 63;
    int c = lane & 15, g = lane >> 4;

    bf16x8 q8 = *(const bf16x8*)(Qb + (size_t)p * 128 + c * 8);
    float qf[8];
#pragma unroll
    for (int j = 0; j < 8; ++j) qf[j] = (float)q8[j];

    int s0 = offb[p], e0 = offb[p + 1];
    float acc[8] = {};

    int i = s0 + g;
    for (; i + 12 < e0; i += 16) {
        int n0 = csrc[i], n1 = csrc[i + 4], n2 = csrc[i + 8], n3 = csrc[i + 12];
        const bf16_t* b0 = KVb + (size_t)n0 * 256 + c * 8;
        const bf16_t* b1 = KVb + (size_t)n1 * 256 + c * 8;
        const bf16_t* b2 = KVb + (size_t)n2 * 256 + c * 8;
        const bf16_t* b3 = KVb + (size_t)n3 * 256 + c * 8;
        bf16x8 k0 = *(const bf16x8*)b0, v0 = *(const bf16x8*)(b0 + 128);
        bf16x8 k1 = *(const bf16x8*)b1, v1 = *(const bf16x8*)(b1 + 128);
        bf16x8 k2 = *(const bf16x8*)b2, v2 = *(const bf16x8*)(b2 + 128);
        bf16x8 k3 = *(const bf16x8*)b3, v3 = *(const bf16x8*)(b3 + 128);
        float d0 = 0.f, d1 = 0.f, d2 = 0.f, d3 = 0.f;
#pragma unroll
        for (int j = 0; j < 8; ++j) {
            d0 += qf[j] * (float)k0[j]; d1 += qf[j] * (float)k1[j];
            d2 += qf[j] * (float)k2[j]; d3 += qf[j] * (float)k3[j];
        }
        d0 += __shfl_xor(d0, 1); d1 += __shfl_xor(d1, 1); d2 += __shfl_xor(d2, 1); d3 += __shfl_xor(d3, 1);
        d0 += __shfl_xor(d0, 2); d1 += __shfl_xor(d1, 2); d2 += __shfl_xor(d2, 2); d3 += __shfl_xor(d3, 2);
        d0 += __shfl_xor(d0, 4); d1 += __shfl_xor(d1, 4); d2 += __shfl_xor(d2, 4); d3 += __shfl_xor(d3, 4);
        d0 += __shfl_xor(d0, 8); d1 += __shfl_xor(d1, 8); d2 += __shfl_xor(d2, 8); d3 += __shfl_xor(d3, 8);
        float a0 = fmaxf(d0 * 0.1f, 0.f), a1 = fmaxf(d1 * 0.1f, 0.f);
        float a2 = fmaxf(d2 * 0.1f, 0.f), a3 = fmaxf(d3 * 0.1f, 0.f);
#pragma unroll
        for (int j = 0; j < 8; ++j)
            acc[j] += a0 * (float)v0[j] + a1 * (float)v1[j]
                    + a2 * (float)v2[j] + a3 * (float)v3[j];
    }
    for (; i < e0; i += 4) {
        int nA = csrc[i];
        const bf16_t* bA = KVb + (size_t)nA * 256 + c * 8;
        bf16x8 kA = *(const bf16x8*)bA;
        bf16x8 vA = *(const bf16x8*)(bA + 128);
        float dA = 0.f;
#pragma unroll
        for (int j = 0; j < 8; ++j) dA += qf[j] * (float)kA[j];
        dA += __shfl_xor(dA, 1);
        dA += __shfl_xor(dA, 2);
        dA += __shfl_xor(dA, 4);
        dA += __shfl_xor(dA, 8);
        float aA = fmaxf(dA * 0.1f, 0.f);
#pragma unroll
        for (int j = 0; j < 8; ++j) acc[j] += aA * (float)vA[j];
    }

#pragma unroll
    for (int j = 0; j < 8; ++j) {
        acc[j] += __shfl_xor(acc[j], 16);
        acc[j] += __shfl_xor(acc[j], 32);
    }

    float ss = 0.f;
#pragma unroll
    for (int j = 0; j < 8; ++j) ss += acc[j] * acc[j];
    ss += __shfl_xor(ss, 1); ss += __shfl_xor(ss, 2); ss += __shfl_xor(ss, 4); ss += __shfl_xor(ss, 8);
    float scale = rsqrtf(ss * (1.f / 128.f) + 1e-6f);
    if (g == 0) {
        int cb = c * 8;
        const float* hp = ph + (size_t)p * 128 + cb;
        float4 ha = *(const float4*)hp, hb = *(const float4*)(hp + 4);
        float hv[8] = {ha.x, ha.y, ha.z, ha.w, hb.x, hb.y, hb.z, hb.w};
        bf16x8 gv, hvb;
#pragma unroll
        for (int j = 0; j < 8; ++j) {
            float wsv = acc[j];
            float rv = wsv * scale * rms_w[cb + j];
            gv[j] = (bf16_t)(rv * sigmoidf_(wsv * lin_w[cb + j]));
            hvb[j] = (bf16_t)hv[j];
        }
        *(bf16x8*)(AG + (size_t)p * 256 + cb) = gv;
        *(bf16x8*)(AG + (size_t)p * 256 + 128 + cb) = hvb;
    }
}

// ------------------------------------------------------------------
// gru+ln pointwise (unchanged): G768 fp32 -> h_new -> LN -> LNb bf16
// ------------------------------------------------------------------
__global__ void gru_ln_kernel(const float* __restrict__ G768, const float* __restrict__ ph,
                              const float* __restrict__ ln_g, const float* __restrict__ ln_b,
                              bf16_t* __restrict__ LNb, int P_, int Mq)
{
    int tid = threadIdx.x;
    int g = tid >> 4, s = tid & 15;
    int p = blockIdx.x * 16 + g;
    if (p >= Mq) return;
    int cb = s * 8;
    if (p >= P_) {
        bf16x8 z = {};
        *(bf16x8*)(LNb + (size_t)p * 128 + cb) = z;
        return;
    }
    const float* G = G768 + (size_t)p * 768;
    float ir[8], iz[8], in_[8], hr[8], hz[8], hn_[8], hv[8];
#pragma unroll
    for (int q = 0; q < 2; ++q) {
        float4 v;
        v = *(const float4*)(G + cb + q * 4);        ir[q*4]=v.x; ir[q*4+1]=v.y; ir[q*4+2]=v.z; ir[q*4+3]=v.w;
        v = *(const float4*)(G + 128 + cb + q * 4);  iz[q*4]=v.x; iz[q*4+1]=v.y; iz[q*4+2]=v.z; iz[q*4+3]=v.w;
        v = *(const float4*)(G + 256 + cb + q * 4);  in_[q*4]=v.x; in_[q*4+1]=v.y; in_[q*4+2]=v.z; in_[q*4+3]=v.w;
        v = *(const float4*)(G + 384 + cb + q * 4);  hr[q*4]=v.x; hr[q*4+1]=v.y; hr[q*4+2]=v.z; hr[q*4+3]=v.w;
        v = *(const float4*)(G + 512 + cb + q * 4);  hz[q*4]=v.x; hz[q*4+1]=v.y; hz[q*4+2]=v.z; hz[q*4+3]=v.w;
        v = *(const float4*)(G + 640 + cb + q * 4);  hn_[q*4]=v.x; hn_[q*4+1]=v.y; hn_[q*4+2]=v.z; hn_[q*4+3]=v.w;
        v = *(const float4*)(ph + (size_t)p * 128 + cb + q * 4);
        hv[q*4]=v.x; hv[q*4+1]=v.y; hv[q*4+2]=v.z; hv[q*4+3]=v.w;
    }
    float hn[8];
    float sm = 0.f, sq = 0.f;
#pragma unroll
    for (int j = 0; j < 8; ++j) {
        float r = sigmoidf_(ir[j] + hr[j]);
        float z = sigmoidf_(iz[j] + hz[j]);
        float n = tanhf(in_[j] + r * hn_[j]);
        hn[j] = (1.f - z) * n + z * hv[j];
        sm += hn[j]; sq += hn[j] * hn[j];
    }
    sm += __shfl_xor(sm, 1); sm += __shfl_xor(sm, 2); sm += __shfl_xor(sm, 4); sm += __shfl_xor(sm, 8);
    sq += __shfl_xor(sq, 1); sq += __shfl_xor(sq, 2); sq += __shfl_xor(sq, 4); sq += __shfl_xor(sq, 8);
    float mu = sm * (1.f / 128.f);
    float var = sq * (1.f / 128.f) - mu * mu;
    float iv = rsqrtf(var + 1e-5f);
    bf16x8 o;
#pragma unroll
    for (int j = 0; j < 8; ++j) {
        int c = cb + j;
        o[j] = (bf16_t)((hn[j] - mu) * iv * ln_g[c] + ln_b[c]);
    }
    *(bf16x8*)(LNb + (size_t)p * 128 + cb) = o;
}

// ------------------------------------------------------------------
// mlp_kernel: fused MLP1+relu+MLP2+residual (VALU, r1-verified pattern).
// 16 particles/block; thread (g=tid>>4, s=tid&15) owns 8 cols.
// Weights re-read per block (W1 32KB + W2 32KB fp32 -> L2-resident).
// ------------------------------------------------------------------
__global__ __launch_bounds__(256) void mlp_kernel(
    const bf16_t* __restrict__ LNb, const float* __restrict__ ph,
    const float* __restrict__ W1, const float* __restrict__ b1,
    const float* __restrict__ W2, const float* __restrict__ b2,
    float* __restrict__ out, int P_)
{
    __shared__ float lnl[16 * 132];
    __shared__ float h1l[16 * 68];
    int tid = threadIdx.x;
    int g = tid >> 4, s = tid & 15;
    int p0 = blockIdx.x * 16;
    int p = p0 + g;

    for (int i = tid; i < 16 * 128; i += 256) {
        int row = i >> 7, c = i & 127;
        lnl[row * 132 + c] = (float)LNb[(size_t)(p0 + row) * 128 + c];
    }
    __syncthreads();

    // MLP1: each thread computes 4 of 64 hidden units
    int m0 = s * 4;
    float am[4] = {b1[m0], b1[m0 + 1], b1[m0 + 2], b1[m0 + 3]};
    for (int k = 0; k < 128; ++k) {
        float lk = lnl[g * 132 + k];
        float4 w = *(const float4*)(W1 + k * 64 + m0);
        am[0] += lk * w.x; am[1] += lk * w.y; am[2] += lk * w.z; am[3] += lk * w.w;
    }
    h1l[g * 68 + m0 + 0] = fmaxf(am[0], 0.f);
    h1l[g * 68 + m0 + 1] = fmaxf(am[1], 0.f);
    h1l[g * 68 + m0 + 2] = fmaxf(am[2], 0.f);
    h1l[g * 68 + m0 + 3] = fmaxf(am[3], 0.f);
    __syncthreads();

    // MLP2 + residual (original h)
    if (p >= P_) return;
    int cb = s * 8;
    const float* hp = ph + (size_t)p * 128 + cb;
    float4 ha = *(const float4*)hp, hb = *(const float4*)(hp + 4);
    float o[8] = {ha.x + b2[cb], ha.y + b2[cb + 1], ha.z + b2[cb + 2], ha.w + b2[cb + 3],
                  hb.x + b2[cb + 4], hb.y + b2[cb + 5], hb.z + b2[cb + 6], hb.w + b2[cb + 7]};
    for (int m = 0; m < 64; ++m) {
        float hm = h1l[g * 68 + m];
        const float* wp = W2 + m * 128 + cb;
        float4 wa = *(const float4*)wp, wb = *(const float4*)(wp + 4);
        o[0] += hm * wa.x; o[1] += hm * wa.y; o[2] += hm * wa.z; o[3] += hm * wa.w;
        o[4] += hm * wb.x; o[5] += hm * wb.y; o[6] += hm * wb.z; o[7] += hm * wb.w;
    }
    *(float4*)(out + (size_t)p * 128 + cb)     = make_float4(o[0], o[1], o[2], o[3]);
    *(float4*)(out + (size_t)p * 128 + cb + 4) = make_float4(o[4], o[5], o[6], o[7]);
}

// ------------------------------------------------------------------
extern "C" void kernel_launch(void* const* d_in, const int* in_sizes, int n_in,
                              void* d_out, int out_size, void* d_ws, size_t ws_size,
                              hipStream_t stream)
{
    const float* nh      = (const float*)d_in[0];
    const float* energy  = (const float*)d_in[1];
    const float* eta     = (const float*)d_in[2];
    const float* phi     = (const float*)d_in[3];
    const float* layer   = (const float*)d_in[4];
    const float* eta_l   = (const float*)d_in[5];
    const float* phi_l   = (const float*)d_in[6];
    const float* ene_l   = (const float*)d_in[7];
    const float* track   = (const float*)d_in[8];
    const float* ph      = (const float*)d_in[9];
    const float* grep    = (const float*)d_in[10];
    const int*   esrc    = (const int*)d_in[11];
    const int*   edst    = (const int*)d_in[12];
    const float* W_key   = (const float*)d_in[13];
    const float* b_key   = (const float*)d_in[14];
    const float* W_val   = (const float*)d_in[15];
    const float* b_val   = (const float*)d_in[16];
    const float* W_q     = (const float*)d_in[17];
    const float* b_q     = (const float*)d_in[18];
    const float* W_ih    = (const float*)d_in[19];
    const float* b_ih    = (const float*)d_in[20];
    const float* W_hh    = (const float*)d_in[21];
    const float* b_hh    = (const float*)d_in[22];
    const float* ln_g    = (const float*)d_in[23];
    const float* ln_b    = (const float*)d_in[24];
    const float* W1      = (const float*)d_in[25];
    const float* b1      = (const float*)d_in[26];
    const float* W2      = (const float*)d_in[27];
    const float* b2      = (const float*)d_in[28];
    const float* rms_w   = (const float*)d_in[29];
    const float* lin_w   = (const float*)d_in[30];

    const int N = in_sizes[1];
    const int P = in_sizes[9] / 128;
    const int E = in_sizes[11];
    const int Mpad = ((N + 127) / 128) * 128;   // 100096
    const int Mq   = ((P + 127) / 128) * 128;   // 10112

    // workspace layout (byte offsets, 256B aligned)
    char* base = (char*)d_ws;
    size_t off = 0;
    auto alloc = [&](size_t bytes) { void* p = base + off; off = (off + bytes + 255) & ~(size_t)255; return p; };
    bf16_t* skipb = (bf16_t*)alloc((size_t)Mpad * 32 * 2);
    bf16_t* WbfT  = (bf16_t*)alloc(256 * 288 * 2);
    bf16_t* WqT   = (bf16_t*)alloc(128 * 384 * 2);
    float*  bpn   = (float*)alloc(256 * 4);
    float*  bpq   = (float*)alloc(128 * 4);
    bf16_t* KVb   = (bf16_t*)alloc((size_t)Mpad * 256 * 2);
    bf16_t* Qb    = (bf16_t*)alloc((size_t)Mq * 128 * 2);
    // cnt and cur MUST be contiguous: prep_all zeroes cnt[0..2P)
    int*    cnt   = (int*)alloc((size_t)(2 * P) * 4);
    int*    cur   = cnt + P;
    int*    offb  = (int*)alloc((size_t)(P + 1) * 4);
    int*    csrc  = (int*)alloc((size_t)E * 4);
    bf16_t* AG    = (bf16_t*)alloc((size_t)Mq * 256 * 2);
    bf16_t* BTg   = (bf16_t*)alloc(768 * 256 * 2);
    float*  bgru  = (float*)alloc(768 * 4);
    float*  G768  = (float*)alloc((size_t)Mq * 768 * 4);
    bf16_t* LNb   = (bf16_t*)alloc((size_t)Mq * 128 * 2);

    // 1. merged weight prep (+ cnt zero + AG pad zero) + skip features
    {
        int padElems = (Mq - P) * 256;
        int T1 = 256 * 288 + 128 * 384 + 256 + 128;
        int T2 = 768 * 256 + 768 + 2 * P + padElems;
        prep_all<<<(T1 + T2 + THREADS - 1) / THREADS, THREADS, 0, stream>>>(
            W_key, W_val, W_q, b_key, b_val, b_q, WbfT, WqT, bpn, bpq,
            W_ih, W_hh, b_ih, b_hh, BTg, bgru, cnt, 2 * P, AG, P, padElems);
        skip_kernel<<<(Mpad + THREADS - 1) / THREADS, THREADS, 0, stream>>>(
            energy, eta, phi, layer, eta_l, phi_l, ene_l, track, skipb, N, Mpad);
    }
    // 2. K/V GEMM (single-wave WGs) + Q GEMM
    kv_gemm1w<<<dim3(Mpad / 32, 4), 64, 0, stream>>>(nh, skipb, WbfT, bpn, KVb, N);
    mfma_gemm<1><<<dim3(1, Mq / 64), THREADS, 0, stream>>>(
        ph, grep, WqT, bpq, Qb, 384, P);
    // 3. CSR build
    hist_kernel<<<(E + THREADS - 1) / THREADS, THREADS, 0, stream>>>(edst, cnt, E);
    scan_kernel<<<1, 1024, 0, stream>>>(cnt, offb, P);
    fill_src_kernel<<<(E + THREADS - 1) / THREADS, THREADS, 0, stream>>>(
        edst, esrc, offb, cur, csrc, E);
    // 4. fused attention + gather + gate -> AG
    edge_kernel<<<(P + 3) / 4, THREADS, 0, stream>>>(
        offb, csrc, KVb, Qb, ph, rms_w, lin_w, AG, P);
    // 5. node update: GRU GEMM -> GRU/LN pointwise -> fused MLP+residual
    mfma_gemm<2><<<dim3(6, Mq / 64), THREADS, 0, stream>>>(
        AG, nullptr, BTg, bgru, G768, 256, Mq);
    gru_ln_kernel<<<Mq / 16, THREADS, 0, stream>>>(G768, ph, ln_g, ln_b, LNb, P, Mq);
    mlp_kernel<<<Mq / 16, THREADS, 0, stream>>>(LNb, ph, W1, b1, W2, b2, (float*)d_out, P);
}

// Round 15
// 234.686 us; speedup vs baseline: 1.1126x; 1.1126x over previous
//
#include <hip/hip_runtime.h>
#include <hip/hip_bf16.h>
#include <math.h>

#define THREADS 256

typedef __bf16 bf16_t;
typedef __bf16 bf16x8 __attribute__((ext_vector_type(8)));
typedef float f32x4 __attribute__((ext_vector_type(4)));

__device__ __forceinline__ float sigmoidf_(float x) { return 1.f / (1.f + expf(-x)); }

__device__ __forceinline__ void gload_lds16(const void* g, void* l) {
    __builtin_amdgcn_global_load_lds((const __attribute__((address_space(1))) void*)g,
                                     (__attribute__((address_space(3))) void*)l, 16, 0, 0);
}

__device__ __forceinline__ bf16x8 cvt8(float4 a, float4 b) {
    bf16x8 v;
    v[0] = (bf16_t)a.x; v[1] = (bf16_t)a.y; v[2] = (bf16_t)a.z; v[3] = (bf16_t)a.w;
    v[4] = (bf16_t)b.x; v[5] = (bf16_t)b.y; v[6] = (bf16_t)b.z; v[7] = (bf16_t)b.w;
    return v;
}

// ------------------------------------------------------------------
// prep_all: merged weight prep.
// [0,T1): WbfT [256][288], WqT [128][384], bpn[256], bpq[128].
// [T1,..): BTg [768][256], bgru, cnt zero, AG pad zero.
// ------------------------------------------------------------------
__global__ void prep_all(const float* __restrict__ W_key, const float* __restrict__ W_val,
                         const float* __restrict__ W_q, const float* __restrict__ b_key,
                         const float* __restrict__ b_val, const float* __restrict__ b_q,
                         bf16_t* __restrict__ WbfT, bf16_t* __restrict__ WqT,
                         float* __restrict__ bpn, float* __restrict__ bpq,
                         const float* __restrict__ W_ih, const float* __restrict__ W_hh,
                         const float* __restrict__ b_ih, const float* __restrict__ b_hh,
                         bf16_t* __restrict__ BTg, float* __restrict__ bgru,
                         int* __restrict__ cnt, int twoP,
                         bf16_t* __restrict__ AG, int padStart, int padElems)
{
    int i0 = blockIdx.x * THREADS + threadIdx.x;
    const int NW = 256 * 288, NQ = 128 * 384;
    const int T1 = NW + NQ + 256 + 128;
    if (i0 < T1) {
        int i = i0;
        if (i < NW) {
            int c = i / 288, k = i - c * 288;
            float v = 0.f;
            if (k < 283) {
                if (c < 100) v = W_key[k * 100 + c];
                else if (c >= 128 && c < 256) v = W_val[k * 128 + (c - 128)];
            }
            WbfT[i] = (bf16_t)v;
        } else if (i < NW + NQ) {
            int j = i - NW;
            int c = j / 384, k = j - c * 384;
            WqT[j] = (bf16_t)((c < 100) ? W_q[k * 100 + c] : 0.f);
        } else if (i < NW + NQ + 256) {
            int c = i - NW - NQ;
            bpn[c] = (c < 100) ? b_key[c] : ((c >= 128 && c < 256) ? b_val[c - 128] : 0.f);
        } else {
            int c = i - NW - NQ - 256;
            bpq[c] = (c < 100) ? b_q[c] : 0.f;
        }
        return;
    }
    int i = i0 - T1;
    const int NG = 768 * 256;
    if (i < NG) {
        int c = i >> 8, k = i & 255;
        float v = 0.f;
        if (c < 384) { if (k < 128) v = W_ih[k * 384 + c]; }
        else         { if (k >= 128) v = W_hh[(k - 128) * 384 + (c - 384)]; }
        BTg[i] = (bf16_t)v;
    } else if (i < NG + 768) {
        int c = i - NG;
        bgru[c] = (c < 384) ? b_ih[c] : b_hh[c - 384];
    } else if (i < NG + 768 + twoP) {
        cnt[i - NG - 768] = 0;
    } else if (i < NG + 768 + twoP + padElems) {
        int j = i - NG - 768 - twoP;
        AG[(size_t)padStart * 256 + j] = (bf16_t)0.f;
    }
}

// skip features -> skipb bf16 [Mpad,32] (27 real + 5 zero; pad rows zero)
__global__ void skip_kernel(const float* __restrict__ energy, const float* __restrict__ eta,
                            const float* __restrict__ phi, const float* __restrict__ layer,
                            const float* __restrict__ eta_l, const float* __restrict__ phi_l,
                            const float* __restrict__ ene_l, const float* __restrict__ track,
                            bf16_t* __restrict__ skipb, int N_, int Mpad)
{
    int n = blockIdx.x * THREADS + threadIdx.x;
    if (n >= Mpad) return;
    float o[32];
#pragma unroll
    for (int j = 0; j < 32; ++j) o[j] = 0.f;
    if (n < N_) {
        o[0] = (logf(energy[n]) - 4.0f) * 0.5f;
        o[1] = eta[n] * (1.f / 1.5f);
        o[2] = phi[n];
        o[3] = layer[n];
#pragma unroll
        for (int j = 0; j < 6; ++j) o[4 + j]  = eta_l[n * 6 + j] * (1.f / 1.5f);
#pragma unroll
        for (int j = 0; j < 6; ++j) o[10 + j] = phi_l[n * 6 + j];
#pragma unroll
        for (int j = 0; j < 6; ++j) o[16 + j] = ene_l[n * 6 + j];
#pragma unroll
        for (int j = 0; j < 5; ++j) o[22 + j] = track[n * 5 + j];
    }
    bf16_t* dst = skipb + (size_t)n * 32;
#pragma unroll
    for (int g = 0; g < 4; ++g) {
        bf16x8 v;
#pragma unroll
        for (int j = 0; j < 8; ++j) v[j] = (bf16_t)o[g * 8 + j];
        *(bf16x8*)(dst + g * 8) = v;
    }
}

// ------------------------------------------------------------------
// bf16 MFMA GEMM: 64x128 tile, BK=32, 4 waves (32x64 each), single-
// buffered 12KB LDS, 2-barrier loop — the empirically-best structure
// for the K/V stage (68.7us; beat dbuf/BM128/reg-direct/1-wave variants).
// MODE 0: A = nh fp32 [.,256] | skipb bf16 [.,32]; K=288; out KVb ldc256
// MODE 1: A = ph fp32 [.,128] | grep fp32 [.,256]; K=384; out Qb bf16
// MODE 2: A bf16 stride K; fp32 out ldc=768 (GRU gi|gh)
// ------------------------------------------------------------------
template <int MODE>
__global__ __launch_bounds__(256) void mfma_gemm(
    const void* __restrict__ A0, const void* __restrict__ A1,
    const bf16_t* __restrict__ BT, const float* __restrict__ bias,
    void* __restrict__ out0v, int K, int Nrows)
{
    __shared__ short AsS[64 * 32];   // [row][k] bf16, 64B rows
    __shared__ short BsS[128 * 32];  // [col][k]
    int tid = threadIdx.x;
    int lane = tid & 63, w = tid >> 6;
    int la = lane & 15, hi = lane >> 4;
    int m0 = (w & 1) * 32, n0 = (w >> 1) * 64;
    int row0 = blockIdx.y * 64, col0 = blockIdx.x * 128;

    f32x4 zero4 = {0.f, 0.f, 0.f, 0.f};
    f32x4 acc[2][4];
#pragma unroll
    for (int i = 0; i < 2; ++i)
#pragma unroll
        for (int j = 0; j < 4; ++j) acc[i][j] = zero4;

    const int ra = tid >> 2, ka = (tid & 3) * 8;   // A: 1 chunk (16B) / thread
    const int c1 = tid + 256;                       // B: 2 chunks / thread
    const int rb0 = tid >> 2, kb0 = (tid & 3) * 8;
    const int rb1 = c1 >> 2,  kb1 = (c1 & 3) * 8;

    for (int kt = 0; kt < K; kt += 32) {
        int gmA = row0 + ra;
        if (MODE == 0) {
            if (kt < 256) {  // kt uniform -> no divergence
                bf16x8 v = {};
                if (gmA < Nrows) {
                    const float* s = (const float*)A0 + (size_t)gmA * 256 + kt + ka;
                    v = cvt8(*(const float4*)s, *(const float4*)(s + 4));
                }
                *(bf16x8*)(AsS + (size_t)tid * 8) = v;
            } else {
                gload_lds16((const bf16_t*)A1 + (size_t)gmA * 32 + (kt - 256) + ka,
                            AsS + (size_t)tid * 8);
            }
        } else if (MODE == 1) {
            int gk = kt + ka;
            bf16x8 v = {};
            if (gmA < Nrows) {
                const float* s = (gk < 128) ? ((const float*)A0 + (size_t)gmA * 128 + gk)
                                            : ((const float*)A1 + (size_t)gmA * 256 + (gk - 128));
                v = cvt8(*(const float4*)s, *(const float4*)(s + 4));
            }
            *(bf16x8*)(AsS + (size_t)tid * 8) = v;
        } else {
            gload_lds16((const bf16_t*)A0 + (size_t)gmA * K + kt + ka,
                        AsS + (size_t)tid * 8);
        }
        gload_lds16(BT + (size_t)(col0 + rb0) * K + kt + kb0, BsS + (size_t)tid * 8);
        gload_lds16(BT + (size_t)(col0 + rb1) * K + kt + kb1, BsS + (size_t)c1 * 8);
        __syncthreads();
        bf16x8 a[2], b[4];
#pragma unroll
        for (int i = 0; i < 2; ++i)
            a[i] = *(const bf16x8*)(AsS + (m0 + i * 16 + la) * 32 + hi * 8);
#pragma unroll
        for (int j = 0; j < 4; ++j)
            b[j] = *(const bf16x8*)(BsS + (n0 + j * 16 + la) * 32 + hi * 8);
#pragma unroll
        for (int i = 0; i < 2; ++i)
#pragma unroll
            for (int j = 0; j < 4; ++j)
                acc[i][j] = __builtin_amdgcn_mfma_f32_16x16x32_bf16(a[i], b[j], acc[i][j], 0, 0, 0);
        __syncthreads();
    }

#pragma unroll
    for (int i = 0; i < 2; ++i) {
#pragma unroll
        for (int j = 0; j < 4; ++j) {
            int col = col0 + n0 + j * 16 + la;
            float bb = bias[col];
#pragma unroll
            for (int r = 0; r < 4; ++r) {
                int row = row0 + m0 + i * 16 + hi * 4 + r;
                float v = acc[i][j][r] + bb;
                if (MODE == 0)      ((bf16_t*)out0v)[(size_t)row * 256 + col] = (bf16_t)v;
                else if (MODE == 1) ((bf16_t*)out0v)[(size_t)row * 128 + col] = (bf16_t)v;
                else                ((float*)out0v)[(size_t)row * 768 + col] = v;
            }
        }
    }
}

// ------------------------------------------------------------------
// CSR build (cnt zeroed by prep_all)
// ------------------------------------------------------------------
__global__ void hist_kernel(const int* __restrict__ dst, int* __restrict__ cnt, int E_)
{
    int i = blockIdx.x * THREADS + threadIdx.x;
    if (i < E_) atomicAdd(&cnt[dst[i]], 1);
}

__global__ void scan_kernel(const int* __restrict__ cnt, int* __restrict__ offb, int P_)
{
    __shared__ int wsum[16];
    int tid = threadIdx.x;
    int lane = tid & 63, w = tid >> 6;
    int base = tid * 10;
    int c[10];
    int s = 0;
#pragma unroll
    for (int j = 0; j < 10; ++j) {
        int i = base + j;
        c[j] = (i < P_) ? cnt[i] : 0;
        s += c[j];
    }
    int pre = s;
    for (int o = 1; o < 64; o <<= 1) {
        int t = __shfl_up(pre, o);
        if (lane >= o) pre += t;
    }
    if (lane == 63) wsum[w] = pre;
    __syncthreads();
    if (w == 0 && lane < 16) {
        int v = wsum[lane];
        for (int o = 1; o < 16; o <<= 1) {
            int t = __shfl_up(v, o, 16);
            if (lane >= o) v += t;
        }
        wsum[lane] = v;
    }
    __syncthreads();
    int waveoff = (w == 0) ? 0 : wsum[w - 1];
    int run = waveoff + pre - s;
#pragma unroll
    for (int j = 0; j < 10; ++j) {
        int i = base + j;
        if (i <= P_) offb[i] = run;
        run += c[j];
    }
}

__global__ void fill_src_kernel(const int* __restrict__ dst, const int* __restrict__ src,
                                const int* __restrict__ offb, int* __restrict__ cur,
                                int* __restrict__ csrc, int E_)
{
    int i = blockIdx.x * THREADS + threadIdx.x;
    if (i < E_) {
        int d = dst[i];
        int pos = atomicAdd(&cur[d], 1);
        csrc[offb[d] + pos] = src[i];
    }
}

// ------------------------------------------------------------------
// fused attention + gather + rms/sigmoid gate (unchanged, proven)
// ------------------------------------------------------------------
__global__ __launch_bounds__(256) void edge_kernel(
    const int* __restrict__ offb, const int* __restrict__ csrc,
    const bf16_t* __restrict__ KVb, const bf16_t* __restrict__ Qb,
    const float* __restrict__ ph, const float* __restrict__ rms_w,
    const float* __restrict__ lin_w, bf16_t* __restrict__ AG, int P_)
{
    int tid = threadIdx.x;
    int p = blockIdx.x * 4 + (tid >> 6);
    if (p >= P_) return;
    int lane = tid & 63;
    int c = lane & 15, g = lane >> 4;

    bf16x8 q8 = *(const bf16x8*)(Qb + (size_t)p * 128 + c * 8);
    float qf[8];
#pragma unroll
    for (int j = 0; j < 8; ++j) qf[j] = (float)q8[j];

    int s0 = offb[p], e0 = offb[p + 1];
    float acc[8] = {};

    int i = s0 + g;
    for (; i + 12 < e0; i += 16) {
        int n0 = csrc[i], n1 = csrc[i + 4], n2 = csrc[i + 8], n3 = csrc[i + 12];
        const bf16_t* b0 = KVb + (size_t)n0 * 256 + c * 8;
        const bf16_t* b1 = KVb + (size_t)n1 * 256 + c * 8;
        const bf16_t* b2 = KVb + (size_t)n2 * 256 + c * 8;
        const bf16_t* b3 = KVb + (size_t)n3 * 256 + c * 8;
        bf16x8 k0 = *(const bf16x8*)b0, v0 = *(const bf16x8*)(b0 + 128);
        bf16x8 k1 = *(const bf16x8*)b1, v1 = *(const bf16x8*)(b1 + 128);
        bf16x8 k2 = *(const bf16x8*)b2, v2 = *(const bf16x8*)(b2 + 128);
        bf16x8 k3 = *(const bf16x8*)b3, v3 = *(const bf16x8*)(b3 + 128);
        float d0 = 0.f, d1 = 0.f, d2 = 0.f, d3 = 0.f;
#pragma unroll
        for (int j = 0; j < 8; ++j) {
            d0 += qf[j] * (float)k0[j]; d1 += qf[j] * (float)k1[j];
            d2 += qf[j] * (float)k2[j]; d3 += qf[j] * (float)k3[j];
        }
        d0 += __shfl_xor(d0, 1); d1 += __shfl_xor(d1, 1); d2 += __shfl_xor(d2, 1); d3 += __shfl_xor(d3, 1);
        d0 += __shfl_xor(d0, 2); d1 += __shfl_xor(d1, 2); d2 += __shfl_xor(d2, 2); d3 += __shfl_xor(d3, 2);
        d0 += __shfl_xor(d0, 4); d1 += __shfl_xor(d1, 4); d2 += __shfl_xor(d2, 4); d3 += __shfl_xor(d3, 4);
        d0 += __shfl_xor(d0, 8); d1 += __shfl_xor(d1, 8); d2 += __shfl_xor(d2, 8); d3 += __shfl_xor(d3, 8);
        float a0 = fmaxf(d0 * 0.1f, 0.f), a1 = fmaxf(d1 * 0.1f, 0.f);
        float a2 = fmaxf(d2 * 0.1f, 0.f), a3 = fmaxf(d3 * 0.1f, 0.f);
#pragma unroll
        for (int j = 0; j < 8; ++j)
            acc[j] += a0 * (float)v0[j] + a1 * (float)v1[j]
                    + a2 * (float)v2[j] + a3 * (float)v3[j];
    }
    for (; i < e0; i += 4) {
        int nA = csrc[i];
        const bf16_t* bA = KVb + (size_t)nA * 256 + c * 8;
        bf16x8 kA = *(const bf16x8*)bA;
        bf16x8 vA = *(const bf16x8*)(bA + 128);
        float dA = 0.f;
#pragma unroll
        for (int j = 0; j < 8; ++j) dA += qf[j] * (float)kA[j];
        dA += __shfl_xor(dA, 1);
        dA += __shfl_xor(dA, 2);
        dA += __shfl_xor(dA, 4);
        dA += __shfl_xor(dA, 8);
        float aA = fmaxf(dA * 0.1f, 0.f);
#pragma unroll
        for (int j = 0; j < 8; ++j) acc[j] += aA * (float)vA[j];
    }

#pragma unroll
    for (int j = 0; j < 8; ++j) {
        acc[j] += __shfl_xor(acc[j], 16);
        acc[j] += __shfl_xor(acc[j], 32);
    }

    float ss = 0.f;
#pragma unroll
    for (int j = 0; j < 8; ++j) ss += acc[j] * acc[j];
    ss += __shfl_xor(ss, 1); ss += __shfl_xor(ss, 2); ss += __shfl_xor(ss, 4); ss += __shfl_xor(ss, 8);
    float scale = rsqrtf(ss * (1.f / 128.f) + 1e-6f);
    if (g == 0) {
        int cb = c * 8;
        const float* hp = ph + (size_t)p * 128 + cb;
        float4 ha = *(const float4*)hp, hb = *(const float4*)(hp + 4);
        float hv[8] = {ha.x, ha.y, ha.z, ha.w, hb.x, hb.y, hb.z, hb.w};
        bf16x8 gv, hvb;
#pragma unroll
        for (int j = 0; j < 8; ++j) {
            float wsv = acc[j];
            float rv = wsv * scale * rms_w[cb + j];
            gv[j] = (bf16_t)(rv * sigmoidf_(wsv * lin_w[cb + j]));
            hvb[j] = (bf16_t)hv[j];
        }
        *(bf16x8*)(AG + (size_t)p * 256 + cb) = gv;
        *(bf16x8*)(AG + (size_t)p * 256 + 128 + cb) = hvb;
    }
}

// ------------------------------------------------------------------
// gru+ln pointwise: G768 fp32 (gi|gh) -> h_new -> LN -> LNb bf16
// ------------------------------------------------------------------
__global__ void gru_ln_kernel(const float* __restrict__ G768, const float* __restrict__ ph,
                              const float* __restrict__ ln_g, const float* __restrict__ ln_b,
                              bf16_t* __restrict__ LNb, int P_, int Mq)
{
    int tid = threadIdx.x;
    int g = tid >> 4, s = tid & 15;
    int p = blockIdx.x * 16 + g;
    if (p >= Mq) return;
    int cb = s * 8;
    if (p >= P_) {
        bf16x8 z = {};
        *(bf16x8*)(LNb + (size_t)p * 128 + cb) = z;
        return;
    }
    const float* G = G768 + (size_t)p * 768;
    float ir[8], iz[8], in_[8], hr[8], hz[8], hn_[8], hv[8];
#pragma unroll
    for (int q = 0; q < 2; ++q) {
        float4 v;
        v = *(const float4*)(G + cb + q * 4);        ir[q*4]=v.x; ir[q*4+1]=v.y; ir[q*4+2]=v.z; ir[q*4+3]=v.w;
        v = *(const float4*)(G + 128 + cb + q * 4);  iz[q*4]=v.x; iz[q*4+1]=v.y; iz[q*4+2]=v.z; iz[q*4+3]=v.w;
        v = *(const float4*)(G + 256 + cb + q * 4);  in_[q*4]=v.x; in_[q*4+1]=v.y; in_[q*4+2]=v.z; in_[q*4+3]=v.w;
        v = *(const float4*)(G + 384 + cb + q * 4);  hr[q*4]=v.x; hr[q*4+1]=v.y; hr[q*4+2]=v.z; hr[q*4+3]=v.w;
        v = *(const float4*)(G + 512 + cb + q * 4);  hz[q*4]=v.x; hz[q*4+1]=v.y; hz[q*4+2]=v.z; hz[q*4+3]=v.w;
        v = *(const float4*)(G + 640 + cb + q * 4);  hn_[q*4]=v.x; hn_[q*4+1]=v.y; hn_[q*4+2]=v.z; hn_[q*4+3]=v.w;
        v = *(const float4*)(ph + (size_t)p * 128 + cb + q * 4);
        hv[q*4]=v.x; hv[q*4+1]=v.y; hv[q*4+2]=v.z; hv[q*4+3]=v.w;
    }
    float hn[8];
    float sm = 0.f, sq = 0.f;
#pragma unroll
    for (int j = 0; j < 8; ++j) {
        float r = sigmoidf_(ir[j] + hr[j]);
        float z = sigmoidf_(iz[j] + hz[j]);
        float n = tanhf(in_[j] + r * hn_[j]);
        hn[j] = (1.f - z) * n + z * hv[j];
        sm += hn[j]; sq += hn[j] * hn[j];
    }
    sm += __shfl_xor(sm, 1); sm += __shfl_xor(sm, 2); sm += __shfl_xor(sm, 4); sm += __shfl_xor(sm, 8);
    sq += __shfl_xor(sq, 1); sq += __shfl_xor(sq, 2); sq += __shfl_xor(sq, 4); sq += __shfl_xor(sq, 8);
    float mu = sm * (1.f / 128.f);
    float var = sq * (1.f / 128.f) - mu * mu;
    float iv = rsqrtf(var + 1e-5f);
    bf16x8 o;
#pragma unroll
    for (int j = 0; j < 8; ++j) {
        int c = cb + j;
        o[j] = (bf16_t)((hn[j] - mu) * iv * ln_g[c] + ln_b[c]);
    }
    *(bf16x8*)(LNb + (size_t)p * 128 + cb) = o;
}

// ------------------------------------------------------------------
// mlp_kernel: fused MLP1+relu+MLP2+residual (fp32 VALU, r14-verified)
// ------------------------------------------------------------------
__global__ __launch_bounds__(256) void mlp_kernel(
    const bf16_t* __restrict__ LNb, const float* __restrict__ ph,
    const float* __restrict__ W1, const float* __restrict__ b1,
    const float* __restrict__ W2, const float* __restrict__ b2,
    float* __restrict__ out, int P_)
{
    __shared__ float lnl[16 * 132];
    __shared__ float h1l[16 * 68];
    int tid = threadIdx.x;
    int g = tid >> 4, s = tid & 15;
    int p0 = blockIdx.x * 16;
    int p = p0 + g;

    for (int i = tid; i < 16 * 128; i += 256) {
        int row = i >> 7, c = i & 127;
        lnl[row * 132 + c] = (float)LNb[(size_t)(p0 + row) * 128 + c];
    }
    __syncthreads();

    int m0 = s * 4;
    float am[4] = {b1[m0], b1[m0 + 1], b1[m0 + 2], b1[m0 + 3]};
    for (int k = 0; k < 128; ++k) {
        float lk = lnl[g * 132 + k];
        float4 w = *(const float4*)(W1 + k * 64 + m0);
        am[0] += lk * w.x; am[1] += lk * w.y; am[2] += lk * w.z; am[3] += lk * w.w;
    }
    h1l[g * 68 + m0 + 0] = fmaxf(am[0], 0.f);
    h1l[g * 68 + m0 + 1] = fmaxf(am[1], 0.f);
    h1l[g * 68 + m0 + 2] = fmaxf(am[2], 0.f);
    h1l[g * 68 + m0 + 3] = fmaxf(am[3], 0.f);
    __syncthreads();

    if (p >= P_) return;
    int cb = s * 8;
    const float* hp = ph + (size_t)p * 128 + cb;
    float4 ha = *(const float4*)hp, hb = *(const float4*)(hp + 4);
    float o[8] = {ha.x + b2[cb], ha.y + b2[cb + 1], ha.z + b2[cb + 2], ha.w + b2[cb + 3],
                  hb.x + b2[cb + 4], hb.y + b2[cb + 5], hb.z + b2[cb + 6], hb.w + b2[cb + 7]};
    for (int m = 0; m < 64; ++m) {
        float hm = h1l[g * 68 + m];
        const float* wp = W2 + m * 128 + cb;
        float4 wa = *(const float4*)wp, wb = *(const float4*)(wp + 4);
        o[0] += hm * wa.x; o[1] += hm * wa.y; o[2] += hm * wa.z; o[3] += hm * wa.w;
        o[4] += hm * wb.x; o[5] += hm * wb.y; o[6] += hm * wb.z; o[7] += hm * wb.w;
    }
    *(float4*)(out + (size_t)p * 128 + cb)     = make_float4(o[0], o[1], o[2], o[3]);
    *(float4*)(out + (size_t)p * 128 + cb + 4) = make_float4(o[4], o[5], o[6], o[7]);
}

// ------------------------------------------------------------------
extern "C" void kernel_launch(void* const* d_in, const int* in_sizes, int n_in,
                              void* d_out, int out_size, void* d_ws, size_t ws_size,
                              hipStream_t stream)
{
    const float* nh      = (const float*)d_in[0];
    const float* energy  = (const float*)d_in[1];
    const float* eta     = (const float*)d_in[2];
    const float* phi     = (const float*)d_in[3];
    const float* layer   = (const float*)d_in[4];
    const float* eta_l   = (const float*)d_in[5];
    const float* phi_l   = (const float*)d_in[6];
    const float* ene_l   = (const float*)d_in[7];
    const float* track   = (const float*)d_in[8];
    const float* ph      = (const float*)d_in[9];
    const float* grep    = (const float*)d_in[10];
    const int*   esrc    = (const int*)d_in[11];
    const int*   edst    = (const int*)d_in[12];
    const float* W_key   = (const float*)d_in[13];
    const float* b_key   = (const float*)d_in[14];
    const float* W_val   = (const float*)d_in[15];
    const float* b_val   = (const float*)d_in[16];
    const float* W_q     = (const float*)d_in[17];
    const float* b_q     = (const float*)d_in[18];
    const float* W_ih    = (const float*)d_in[19];
    const float* b_ih    = (const float*)d_in[20];
    const float* W_hh    = (const float*)d_in[21];
    const float* b_hh    = (const float*)d_in[22];
    const float* ln_g    = (const float*)d_in[23];
    const float* ln_b    = (const float*)d_in[24];
    const float* W1      = (const float*)d_in[25];
    const float* b1      = (const float*)d_in[26];
    const float* W2      = (const float*)d_in[27];
    const float* b2      = (const float*)d_in[28];
    const float* rms_w   = (const float*)d_in[29];
    const float* lin_w   = (const float*)d_in[30];

    const int N = in_sizes[1];
    const int P = in_sizes[9] / 128;
    const int E = in_sizes[11];
    const int Mpad = ((N + 127) / 128) * 128;   // 100096
    const int Mq   = ((P + 127) / 128) * 128;   // 10112

    // workspace layout (byte offsets, 256B aligned)
    char* base = (char*)d_ws;
    size_t off = 0;
    auto alloc = [&](size_t bytes) { void* p = base + off; off = (off + bytes + 255) & ~(size_t)255; return p; };
    bf16_t* skipb = (bf16_t*)alloc((size_t)Mpad * 32 * 2);
    bf16_t* WbfT  = (bf16_t*)alloc(256 * 288 * 2);
    bf16_t* WqT   = (bf16_t*)alloc(128 * 384 * 2);
    float*  bpn   = (float*)alloc(256 * 4);
    float*  bpq   = (float*)alloc(128 * 4);
    bf16_t* KVb   = (bf16_t*)alloc((size_t)Mpad * 256 * 2);
    bf16_t* Qb    = (bf16_t*)alloc((size_t)Mq * 128 * 2);
    // cnt and cur MUST be contiguous: prep_all zeroes cnt[0..2P)
    int*    cnt   = (int*)alloc((size_t)(2 * P) * 4);
    int*    cur   = cnt + P;
    int*    offb  = (int*)alloc((size_t)(P + 1) * 4);
    int*    csrc  = (int*)alloc((size_t)E * 4);
    bf16_t* AG    = (bf16_t*)alloc((size_t)Mq * 256 * 2);
    bf16_t* BTg   = (bf16_t*)alloc(768 * 256 * 2);
    float*  bgru  = (float*)alloc(768 * 4);
    float*  G768  = (float*)alloc((size_t)Mq * 768 * 4);
    bf16_t* LNb   = (bf16_t*)alloc((size_t)Mq * 128 * 2);

    // 1. merged weight prep (+ cnt zero + AG pad zero) + skip features
    {
        int padElems = (Mq - P) * 256;
        int T1 = 256 * 288 + 128 * 384 + 256 + 128;
        int T2 = 768 * 256 + 768 + 2 * P + padElems;
        prep_all<<<(T1 + T2 + THREADS - 1) / THREADS, THREADS, 0, stream>>>(
            W_key, W_val, W_q, b_key, b_val, b_q, WbfT, WqT, bpn, bpq,
            W_ih, W_hh, b_ih, b_hh, BTg, bgru, cnt, 2 * P, AG, P, padElems);
        skip_kernel<<<(Mpad + THREADS - 1) / THREADS, THREADS, 0, stream>>>(
            energy, eta, phi, layer, eta_l, phi_l, ene_l, track, skipb, N, Mpad);
    }
    // 2. K/V GEMM (r8/r13 structure, measured best) + Q GEMM
    mfma_gemm<0><<<dim3(2, Mpad / 64), THREADS, 0, stream>>>(
        nh, skipb, WbfT, bpn, KVb, 288, N);
    mfma_gemm<1><<<dim3(1, Mq / 64), THREADS, 0, stream>>>(
        ph, grep, WqT, bpq, Qb, 384, P);
    // 3. CSR build
    hist_kernel<<<(E + THREADS - 1) / THREADS, THREADS, 0, stream>>>(edst, cnt, E);
    scan_kernel<<<1, 1024, 0, stream>>>(cnt, offb, P);
    fill_src_kernel<<<(E + THREADS - 1) / THREADS, THREADS, 0, stream>>>(
        edst, esrc, offb, cur, csrc, E);
    // 4. fused attention + gather + gate -> AG
    edge_kernel<<<(P + 3) / 4, THREADS, 0, stream>>>(
        offb, csrc, KVb, Qb, ph, rms_w, lin_w, AG, P);
    // 5. node update: GRU GEMM -> GRU/LN pointwise -> fused MLP+residual
    mfma_gemm<2><<<dim3(6, Mq / 64), THREADS, 0, stream>>>(
        AG, nullptr, BTg, bgru, G768, 256, Mq);
    gru_ln_kernel<<<Mq / 16, THREADS, 0, stream>>>(G768, ph, ln_g, ln_b, LNb, P, Mq);
    mlp_kernel<<<Mq / 16, THREADS, 0, stream>>>(LNb, ph, W1, b1, W2, b2, (float*)d_out, P);
}

// Round 16
// 231.270 us; speedup vs baseline: 1.1290x; 1.0148x over previous
//
#include <hip/hip_runtime.h>
#include <hip/hip_bf16.h>
#include <math.h>

#define THREADS 256

typedef __bf16 bf16_t;
typedef __bf16 bf16x8 __attribute__((ext_vector_type(8)));
typedef float f32x4 __attribute__((ext_vector_type(4)));

__device__ __forceinline__ float sigmoidf_(float x) { return 1.f / (1.f + expf(-x)); }

__device__ __forceinline__ void gload_lds16(const void* g, void* l) {
    __builtin_amdgcn_global_load_lds((const __attribute__((address_space(1))) void*)g,
                                     (__attribute__((address_space(3))) void*)l, 16, 0, 0);
}

__device__ __forceinline__ bf16x8 cvt8(float4 a, float4 b) {
    bf16x8 v;
    v[0] = (bf16_t)a.x; v[1] = (bf16_t)a.y; v[2] = (bf16_t)a.z; v[3] = (bf16_t)a.w;
    v[4] = (bf16_t)b.x; v[5] = (bf16_t)b.y; v[6] = (bf16_t)b.z; v[7] = (bf16_t)b.w;
    return v;
}

// ------------------------------------------------------------------
// prep_all: merged weight prep.
// [0,T1): WbfT [256][288], WqT [128][384], bpn[256], bpq[128].
// [T1,..): BTg [768][256], bgru, cnt zero, AG pad zero.
// ------------------------------------------------------------------
__global__ void prep_all(const float* __restrict__ W_key, const float* __restrict__ W_val,
                         const float* __restrict__ W_q, const float* __restrict__ b_key,
                         const float* __restrict__ b_val, const float* __restrict__ b_q,
                         bf16_t* __restrict__ WbfT, bf16_t* __restrict__ WqT,
                         float* __restrict__ bpn, float* __restrict__ bpq,
                         const float* __restrict__ W_ih, const float* __restrict__ W_hh,
                         const float* __restrict__ b_ih, const float* __restrict__ b_hh,
                         bf16_t* __restrict__ BTg, float* __restrict__ bgru,
                         int* __restrict__ cnt, int twoP,
                         bf16_t* __restrict__ AG, int padStart, int padElems)
{
    int i0 = blockIdx.x * THREADS + threadIdx.x;
    const int NW = 256 * 288, NQ = 128 * 384;
    const int T1 = NW + NQ + 256 + 128;
    if (i0 < T1) {
        int i = i0;
        if (i < NW) {
            int c = i / 288, k = i - c * 288;
            float v = 0.f;
            if (k < 283) {
                if (c < 100) v = W_key[k * 100 + c];
                else if (c >= 128 && c < 256) v = W_val[k * 128 + (c - 128)];
            }
            WbfT[i] = (bf16_t)v;
        } else if (i < NW + NQ) {
            int j = i - NW;
            int c = j / 384, k = j - c * 384;
            WqT[j] = (bf16_t)((c < 100) ? W_q[k * 100 + c] : 0.f);
        } else if (i < NW + NQ + 256) {
            int c = i - NW - NQ;
            bpn[c] = (c < 100) ? b_key[c] : ((c >= 128 && c < 256) ? b_val[c - 128] : 0.f);
        } else {
            int c = i - NW - NQ - 256;
            bpq[c] = (c < 100) ? b_q[c] : 0.f;
        }
        return;
    }
    int i = i0 - T1;
    const int NG = 768 * 256;
    if (i < NG) {
        int c = i >> 8, k = i & 255;
        float v = 0.f;
        if (c < 384) { if (k < 128) v = W_ih[k * 384 + c]; }
        else         { if (k >= 128) v = W_hh[(k - 128) * 384 + (c - 384)]; }
        BTg[i] = (bf16_t)v;
    } else if (i < NG + 768) {
        int c = i - NG;
        bgru[c] = (c < 384) ? b_ih[c] : b_hh[c - 384];
    } else if (i < NG + 768 + twoP) {
        cnt[i - NG - 768] = 0;
    } else if (i < NG + 768 + twoP + padElems) {
        int j = i - NG - 768 - twoP;
        AG[(size_t)padStart * 256 + j] = (bf16_t)0.f;
    }
}

// skip features -> skipb bf16 [Mpad,32] (27 real + 5 zero; pad rows zero)
__global__ void skip_kernel(const float* __restrict__ energy, const float* __restrict__ eta,
                            const float* __restrict__ phi, const float* __restrict__ layer,
                            const float* __restrict__ eta_l, const float* __restrict__ phi_l,
                            const float* __restrict__ ene_l, const float* __restrict__ track,
                            bf16_t* __restrict__ skipb, int N_, int Mpad)
{
    int n = blockIdx.x * THREADS + threadIdx.x;
    if (n >= Mpad) return;
    float o[32];
#pragma unroll
    for (int j = 0; j < 32; ++j) o[j] = 0.f;
    if (n < N_) {
        o[0] = (logf(energy[n]) - 4.0f) * 0.5f;
        o[1] = eta[n] * (1.f / 1.5f);
        o[2] = phi[n];
        o[3] = layer[n];
#pragma unroll
        for (int j = 0; j < 6; ++j) o[4 + j]  = eta_l[n * 6 + j] * (1.f / 1.5f);
#pragma unroll
        for (int j = 0; j < 6; ++j) o[10 + j] = phi_l[n * 6 + j];
#pragma unroll
        for (int j = 0; j < 6; ++j) o[16 + j] = ene_l[n * 6 + j];
#pragma unroll
        for (int j = 0; j < 5; ++j) o[22 + j] = track[n * 5 + j];
    }
    bf16_t* dst = skipb + (size_t)n * 32;
#pragma unroll
    for (int g = 0; g < 4; ++g) {
        bf16x8 v;
#pragma unroll
        for (int j = 0; j < 8; ++j) v[j] = (bf16_t)o[g * 8 + j];
        *(bf16x8*)(dst + g * 8) = v;
    }
}

// ------------------------------------------------------------------
// bf16 MFMA GEMM: 64x128 tile, BK=32, 4 waves, single-buffered 12KB LDS,
// 2 barriers/step BUT reordered for issue-early/write-late pipelining at
// CONSTANT LDS:  barA(drain stage t) -> ds_read(t) -> barB(reads done,
// LDS dead) -> issue stage(t+1) -> MFMA(t) -> [cvt+ds_write for reg path].
// Next-tile global loads fly during the MFMA window; barA drains them
// only after that window. Same occupancy as r8 (8 blocks/CU).
// MODE 0: A = nh fp32 [.,256] | skipb bf16 [.,32]; K=288; out KVb ldc256
// MODE 1: A = ph fp32 [.,128] | grep fp32 [.,256]; K=384; out Qb bf16
// MODE 2: A bf16 stride K; fp32 out ldc=768 (GRU gi|gh)
// ------------------------------------------------------------------
template <int MODE>
__global__ __launch_bounds__(256) void mfma_gemm(
    const void* __restrict__ A0, const void* __restrict__ A1,
    const bf16_t* __restrict__ BT, const float* __restrict__ bias,
    void* __restrict__ out0v, int K, int Nrows)
{
    __shared__ short AsS[64 * 32];   // [row][k] bf16, 64B rows
    __shared__ short BsS[128 * 32];  // [col][k]
    int tid = threadIdx.x;
    int lane = tid & 63, w = tid >> 6;
    int la = lane & 15, hi = lane >> 4;
    int m0 = (w & 1) * 32, n0 = (w >> 1) * 64;
    int row0 = blockIdx.y * 64, col0 = blockIdx.x * 128;

    f32x4 zero4 = {0.f, 0.f, 0.f, 0.f};
    f32x4 acc[2][4];
#pragma unroll
    for (int i = 0; i < 2; ++i)
#pragma unroll
        for (int j = 0; j < 4; ++j) acc[i][j] = zero4;

    const int ra = tid >> 2, ka = (tid & 3) * 8;   // A: 1 chunk (16B) / thread
    const int c1 = tid + 256;                       // B: 2 chunks / thread
    const int rb0 = tid >> 2, kb0 = (tid & 3) * 8;
    const int rb1 = c1 >> 2,  kb1 = (c1 & 3) * 8;

    float4 fa0, fa1;  // in-flight fp32 A row chunk (reg path)

    // returns true if reg path (needs write-late cvt+ds_write)
    auto issueA = [&](int kt) -> bool {
        int gmA = row0 + ra;
        if (MODE == 0) {
            if (kt < 256) {  // kt uniform -> no divergence
                if (gmA < Nrows) {
                    const float* s = (const float*)A0 + (size_t)gmA * 256 + kt + ka;
                    fa0 = *(const float4*)s;
                    fa1 = *(const float4*)(s + 4);
                } else {
                    fa0 = make_float4(0.f, 0.f, 0.f, 0.f);
                    fa1 = make_float4(0.f, 0.f, 0.f, 0.f);
                }
                return true;
            }
            gload_lds16((const bf16_t*)A1 + (size_t)gmA * 32 + (kt - 256) + ka,
                        AsS + (size_t)tid * 8);
            return false;
        } else if (MODE == 1) {
            int gk = kt + ka;
            if (gmA < Nrows) {
                const float* s = (gk < 128) ? ((const float*)A0 + (size_t)gmA * 128 + gk)
                                            : ((const float*)A1 + (size_t)gmA * 256 + (gk - 128));
                fa0 = *(const float4*)s;
                fa1 = *(const float4*)(s + 4);
            } else {
                fa0 = make_float4(0.f, 0.f, 0.f, 0.f);
                fa1 = make_float4(0.f, 0.f, 0.f, 0.f);
            }
            return true;
        } else {
            gload_lds16((const bf16_t*)A0 + (size_t)gmA * K + kt + ka,
                        AsS + (size_t)tid * 8);
            return false;
        }
    };
    auto writeA = [&]() { *(bf16x8*)(AsS + (size_t)tid * 8) = cvt8(fa0, fa1); };
    auto issueB = [&](int kt) {
        gload_lds16(BT + (size_t)(col0 + rb0) * K + kt + kb0, BsS + (size_t)tid * 8);
        gload_lds16(BT + (size_t)(col0 + rb1) * K + kt + kb1, BsS + (size_t)c1 * 8);
    };

    const int nt = K / 32;
    // prologue: stage tile 0 (synchronous write for reg path)
    {
        bool rp = issueA(0);
        if (rp) writeA();
        issueB(0);
    }
    for (int t = 0; t < nt; ++t) {
        __syncthreads();  // barA: staging of tile t complete (drains vmem/lds writes)
        bf16x8 a[2], b[4];
#pragma unroll
        for (int i = 0; i < 2; ++i)
            a[i] = *(const bf16x8*)(AsS + (m0 + i * 16 + la) * 32 + hi * 8);
#pragma unroll
        for (int j = 0; j < 4; ++j)
            b[j] = *(const bf16x8*)(BsS + (n0 + j * 16 + la) * 32 + hi * 8);
        __syncthreads();  // barB: all waves' reads done -> LDS reusable
        bool have = (t + 1) < nt;
        bool rp = false;
        if (have) {
            rp = issueA((t + 1) * 32);  // loads fly during the MFMA window
            issueB((t + 1) * 32);
        }
#pragma unroll
        for (int i = 0; i < 2; ++i)
#pragma unroll
            for (int j = 0; j < 4; ++j)
                acc[i][j] = __builtin_amdgcn_mfma_f32_16x16x32_bf16(a[i], b[j], acc[i][j], 0, 0, 0);
        if (rp) writeA();  // write-late: cvt+ds_write after MFMA
    }

#pragma unroll
    for (int i = 0; i < 2; ++i) {
#pragma unroll
        for (int j = 0; j < 4; ++j) {
            int col = col0 + n0 + j * 16 + la;
            float bb = bias[col];
#pragma unroll
            for (int r = 0; r < 4; ++r) {
                int row = row0 + m0 + i * 16 + hi * 4 + r;
                float v = acc[i][j][r] + bb;
                if (MODE == 0)      ((bf16_t*)out0v)[(size_t)row * 256 + col] = (bf16_t)v;
                else if (MODE == 1) ((bf16_t*)out0v)[(size_t)row * 128 + col] = (bf16_t)v;
                else                ((float*)out0v)[(size_t)row * 768 + col] = v;
            }
        }
    }
}

// ------------------------------------------------------------------
// CSR build (cnt zeroed by prep_all)
// ------------------------------------------------------------------
__global__ void hist_kernel(const int* __restrict__ dst, int* __restrict__ cnt, int E_)
{
    int i = blockIdx.x * THREADS + threadIdx.x;
    if (i < E_) atomicAdd(&cnt[dst[i]], 1);
}

__global__ void scan_kernel(const int* __restrict__ cnt, int* __restrict__ offb, int P_)
{
    __shared__ int wsum[16];
    int tid = threadIdx.x;
    int lane = tid & 63, w = tid >> 6;
    int base = tid * 10;
    int c[10];
    int s = 0;
#pragma unroll
    for (int j = 0; j < 10; ++j) {
        int i = base + j;
        c[j] = (i < P_) ? cnt[i] : 0;
        s += c[j];
    }
    int pre = s;
    for (int o = 1; o < 64; o <<= 1) {
        int t = __shfl_up(pre, o);
        if (lane >= o) pre += t;
    }
    if (lane == 63) wsum[w] = pre;
    __syncthreads();
    if (w == 0 && lane < 16) {
        int v = wsum[lane];
        for (int o = 1; o < 16; o <<= 1) {
            int t = __shfl_up(v, o, 16);
            if (lane >= o) v += t;
        }
        wsum[lane] = v;
    }
    __syncthreads();
    int waveoff = (w == 0) ? 0 : wsum[w - 1];
    int run = waveoff + pre - s;
#pragma unroll
    for (int j = 0; j < 10; ++j) {
        int i = base + j;
        if (i <= P_) offb[i] = run;
        run += c[j];
    }
}

__global__ void fill_src_kernel(const int* __restrict__ dst, const int* __restrict__ src,
                                const int* __restrict__ offb, int* __restrict__ cur,
                                int* __restrict__ csrc, int E_)
{
    int i = blockIdx.x * THREADS + threadIdx.x;
    if (i < E_) {
        int d = dst[i];
        int pos = atomicAdd(&cur[d], 1);
        csrc[offb[d] + pos] = src[i];
    }
}

// ------------------------------------------------------------------
// fused attention + gather + rms/sigmoid gate (unchanged, proven)
// ------------------------------------------------------------------
__global__ __launch_bounds__(256) void edge_kernel(
    const int* __restrict__ offb, const int* __restrict__ csrc,
    const bf16_t* __restrict__ KVb, const bf16_t* __restrict__ Qb,
    const float* __restrict__ ph, const float* __restrict__ rms_w,
    const float* __restrict__ lin_w, bf16_t* __restrict__ AG, int P_)
{
    int tid = threadIdx.x;
    int p = blockIdx.x * 4 + (tid >> 6);
    if (p >= P_) return;
    int lane = tid & 63;
    int c = lane & 15, g = lane >> 4;

    bf16x8 q8 = *(const bf16x8*)(Qb + (size_t)p * 128 + c * 8);
    float qf[8];
#pragma unroll
    for (int j = 0; j < 8; ++j) qf[j] = (float)q8[j];

    int s0 = offb[p], e0 = offb[p + 1];
    float acc[8] = {};

    int i = s0 + g;
    for (; i + 12 < e0; i += 16) {
        int n0 = csrc[i], n1 = csrc[i + 4], n2 = csrc[i + 8], n3 = csrc[i + 12];
        const bf16_t* b0 = KVb + (size_t)n0 * 256 + c * 8;
        const bf16_t* b1 = KVb + (size_t)n1 * 256 + c * 8;
        const bf16_t* b2 = KVb + (size_t)n2 * 256 + c * 8;
        const bf16_t* b3 = KVb + (size_t)n3 * 256 + c * 8;
        bf16x8 k0 = *(const bf16x8*)b0, v0 = *(const bf16x8*)(b0 + 128);
        bf16x8 k1 = *(const bf16x8*)b1, v1 = *(const bf16x8*)(b1 + 128);
        bf16x8 k2 = *(const bf16x8*)b2, v2 = *(const bf16x8*)(b2 + 128);
        bf16x8 k3 = *(const bf16x8*)b3, v3 = *(const bf16x8*)(b3 + 128);
        float d0 = 0.f, d1 = 0.f, d2 = 0.f, d3 = 0.f;
#pragma unroll
        for (int j = 0; j < 8; ++j) {
            d0 += qf[j] * (float)k0[j]; d1 += qf[j] * (float)k1[j];
            d2 += qf[j] * (float)k2[j]; d3 += qf[j] * (float)k3[j];
        }
        d0 += __shfl_xor(d0, 1); d1 += __shfl_xor(d1, 1); d2 += __shfl_xor(d2, 1); d3 += __shfl_xor(d3, 1);
        d0 += __shfl_xor(d0, 2); d1 += __shfl_xor(d1, 2); d2 += __shfl_xor(d2, 2); d3 += __shfl_xor(d3, 2);
        d0 += __shfl_xor(d0, 4); d1 += __shfl_xor(d1, 4); d2 += __shfl_xor(d2, 4); d3 += __shfl_xor(d3, 4);
        d0 += __shfl_xor(d0, 8); d1 += __shfl_xor(d1, 8); d2 += __shfl_xor(d2, 8); d3 += __shfl_xor(d3, 8);
        float a0 = fmaxf(d0 * 0.1f, 0.f), a1 = fmaxf(d1 * 0.1f, 0.f);
        float a2 = fmaxf(d2 * 0.1f, 0.f), a3 = fmaxf(d3 * 0.1f, 0.f);
#pragma unroll
        for (int j = 0; j < 8; ++j)
            acc[j] += a0 * (float)v0[j] + a1 * (float)v1[j]
                    + a2 * (float)v2[j] + a3 * (float)v3[j];
    }
    for (; i < e0; i += 4) {
        int nA = csrc[i];
        const bf16_t* bA = KVb + (size_t)nA * 256 + c * 8;
        bf16x8 kA = *(const bf16x8*)bA;
        bf16x8 vA = *(const bf16x8*)(bA + 128);
        float dA = 0.f;
#pragma unroll
        for (int j = 0; j < 8; ++j) dA += qf[j] * (float)kA[j];
        dA += __shfl_xor(dA, 1);
        dA += __shfl_xor(dA, 2);
        dA += __shfl_xor(dA, 4);
        dA += __shfl_xor(dA, 8);
        float aA = fmaxf(dA * 0.1f, 0.f);
#pragma unroll
        for (int j = 0; j < 8; ++j) acc[j] += aA * (float)vA[j];
    }

#pragma unroll
    for (int j = 0; j < 8; ++j) {
        acc[j] += __shfl_xor(acc[j], 16);
        acc[j] += __shfl_xor(acc[j], 32);
    }

    float ss = 0.f;
#pragma unroll
    for (int j = 0; j < 8; ++j) ss += acc[j] * acc[j];
    ss += __shfl_xor(ss, 1); ss += __shfl_xor(ss, 2); ss += __shfl_xor(ss, 4); ss += __shfl_xor(ss, 8);
    float scale = rsqrtf(ss * (1.f / 128.f) + 1e-6f);
    if (g == 0) {
        int cb = c * 8;
        const float* hp = ph + (size_t)p * 128 + cb;
        float4 ha = *(const float4*)hp, hb = *(const float4*)(hp + 4);
        float hv[8] = {ha.x, ha.y, ha.z, ha.w, hb.x, hb.y, hb.z, hb.w};
        bf16x8 gv, hvb;
#pragma unroll
        for (int j = 0; j < 8; ++j) {
            float wsv = acc[j];
            float rv = wsv * scale * rms_w[cb + j];
            gv[j] = (bf16_t)(rv * sigmoidf_(wsv * lin_w[cb + j]));
            hvb[j] = (bf16_t)hv[j];
        }
        *(bf16x8*)(AG + (size_t)p * 256 + cb) = gv;
        *(bf16x8*)(AG + (size_t)p * 256 + 128 + cb) = hvb;
    }
}

// ------------------------------------------------------------------
// gru+ln pointwise: G768 fp32 (gi|gh) -> h_new -> LN -> LNb bf16
// ------------------------------------------------------------------
__global__ void gru_ln_kernel(const float* __restrict__ G768, const float* __restrict__ ph,
                              const float* __restrict__ ln_g, const float* __restrict__ ln_b,
                              bf16_t* __restrict__ LNb, int P_, int Mq)
{
    int tid = threadIdx.x;
    int g = tid >> 4, s = tid & 15;
    int p = blockIdx.x * 16 + g;
    if (p >= Mq) return;
    int cb = s * 8;
    if (p >= P_) {
        bf16x8 z = {};
        *(bf16x8*)(LNb + (size_t)p * 128 + cb) = z;
        return;
    }
    const float* G = G768 + (size_t)p * 768;
    float ir[8], iz[8], in_[8], hr[8], hz[8], hn_[8], hv[8];
#pragma unroll
    for (int q = 0; q < 2; ++q) {
        float4 v;
        v = *(const float4*)(G + cb + q * 4);        ir[q*4]=v.x; ir[q*4+1]=v.y; ir[q*4+2]=v.z; ir[q*4+3]=v.w;
        v = *(const float4*)(G + 128 + cb + q * 4);  iz[q*4]=v.x; iz[q*4+1]=v.y; iz[q*4+2]=v.z; iz[q*4+3]=v.w;
        v = *(const float4*)(G + 256 + cb + q * 4);  in_[q*4]=v.x; in_[q*4+1]=v.y; in_[q*4+2]=v.z; in_[q*4+3]=v.w;
        v = *(const float4*)(G + 384 + cb + q * 4);  hr[q*4]=v.x; hr[q*4+1]=v.y; hr[q*4+2]=v.z; hr[q*4+3]=v.w;
        v = *(const float4*)(G + 512 + cb + q * 4);  hz[q*4]=v.x; hz[q*4+1]=v.y; hz[q*4+2]=v.z; hz[q*4+3]=v.w;
        v = *(const float4*)(G + 640 + cb + q * 4);  hn_[q*4]=v.x; hn_[q*4+1]=v.y; hn_[q*4+2]=v.z; hn_[q*4+3]=v.w;
        v = *(const float4*)(ph + (size_t)p * 128 + cb + q * 4);
        hv[q*4]=v.x; hv[q*4+1]=v.y; hv[q*4+2]=v.z; hv[q*4+3]=v.w;
    }
    float hn[8];
    float sm = 0.f, sq = 0.f;
#pragma unroll
    for (int j = 0; j < 8; ++j) {
        float r = sigmoidf_(ir[j] + hr[j]);
        float z = sigmoidf_(iz[j] + hz[j]);
        float n = tanhf(in_[j] + r * hn_[j]);
        hn[j] = (1.f - z) * n + z * hv[j];
        sm += hn[j]; sq += hn[j] * hn[j];
    }
    sm += __shfl_xor(sm, 1); sm += __shfl_xor(sm, 2); sm += __shfl_xor(sm, 4); sm += __shfl_xor(sm, 8);
    sq += __shfl_xor(sq, 1); sq += __shfl_xor(sq, 2); sq += __shfl_xor(sq, 4); sq += __shfl_xor(sq, 8);
    float mu = sm * (1.f / 128.f);
    float var = sq * (1.f / 128.f) - mu * mu;
    float iv = rsqrtf(var + 1e-5f);
    bf16x8 o;
#pragma unroll
    for (int j = 0; j < 8; ++j) {
        int c = cb + j;
        o[j] = (bf16_t)((hn[j] - mu) * iv * ln_g[c] + ln_b[c]);
    }
    *(bf16x8*)(LNb + (size_t)p * 128 + cb) = o;
}

// ------------------------------------------------------------------
// mlp_kernel: fused MLP1+relu+MLP2+residual (fp32 VALU, r14-verified)
// ------------------------------------------------------------------
__global__ __launch_bounds__(256) void mlp_kernel(
    const bf16_t* __restrict__ LNb, const float* __restrict__ ph,
    const float* __restrict__ W1, const float* __restrict__ b1,
    const float* __restrict__ W2, const float* __restrict__ b2,
    float* __restrict__ out, int P_)
{
    __shared__ float lnl[16 * 132];
    __shared__ float h1l[16 * 68];
    int tid = threadIdx.x;
    int g = tid >> 4, s = tid & 15;
    int p0 = blockIdx.x * 16;
    int p = p0 + g;

    for (int i = tid; i < 16 * 128; i += 256) {
        int row = i >> 7, c = i & 127;
        lnl[row * 132 + c] = (float)LNb[(size_t)(p0 + row) * 128 + c];
    }
    __syncthreads();

    int m0 = s * 4;
    float am[4] = {b1[m0], b1[m0 + 1], b1[m0 + 2], b1[m0 + 3]};
    for (int k = 0; k < 128; ++k) {
        float lk = lnl[g * 132 + k];
        float4 w = *(const float4*)(W1 + k * 64 + m0);
        am[0] += lk * w.x; am[1] += lk * w.y; am[2] += lk * w.z; am[3] += lk * w.w;
    }
    h1l[g * 68 + m0 + 0] = fmaxf(am[0], 0.f);
    h1l[g * 68 + m0 + 1] = fmaxf(am[1], 0.f);
    h1l[g * 68 + m0 + 2] = fmaxf(am[2], 0.f);
    h1l[g * 68 + m0 + 3] = fmaxf(am[3], 0.f);
    __syncthreads();

    if (p >= P_) return;
    int cb = s * 8;
    const float* hp = ph + (size_t)p * 128 + cb;
    float4 ha = *(const float4*)hp, hb = *(const float4*)(hp + 4);
    float o[8] = {ha.x + b2[cb], ha.y + b2[cb + 1], ha.z + b2[cb + 2], ha.w + b2[cb + 3],
                  hb.x + b2[cb + 4], hb.y + b2[cb + 5], hb.z + b2[cb + 6], hb.w + b2[cb + 7]};
    for (int m = 0; m < 64; ++m) {
        float hm = h1l[g * 68 + m];
        const float* wp = W2 + m * 128 + cb;
        float4 wa = *(const float4*)wp, wb = *(const float4*)(wp + 4);
        o[0] += hm * wa.x; o[1] += hm * wa.y; o[2] += hm * wa.z; o[3] += hm * wa.w;
        o[4] += hm * wb.x; o[5] += hm * wb.y; o[6] += hm * wb.z; o[7] += hm * wb.w;
    }
    *(float4*)(out + (size_t)p * 128 + cb)     = make_float4(o[0], o[1], o[2], o[3]);
    *(float4*)(out + (size_t)p * 128 + cb + 4) = make_float4(o[4], o[5], o[6], o[7]);
}

// ------------------------------------------------------------------
extern "C" void kernel_launch(void* const* d_in, const int* in_sizes, int n_in,
                              void* d_out, int out_size, void* d_ws, size_t ws_size,
                              hipStream_t stream)
{
    const float* nh      = (const float*)d_in[0];
    const float* energy  = (const float*)d_in[1];
    const float* eta     = (const float*)d_in[2];
    const float* phi     = (const float*)d_in[3];
    const float* layer   = (const float*)d_in[4];
    const float* eta_l   = (const float*)d_in[5];
    const float* phi_l   = (const float*)d_in[6];
    const float* ene_l   = (const float*)d_in[7];
    const float* track   = (const float*)d_in[8];
    const float* ph      = (const float*)d_in[9];
    const float* grep    = (const float*)d_in[10];
    const int*   esrc    = (const int*)d_in[11];
    const int*   edst    = (const int*)d_in[12];
    const float* W_key   = (const float*)d_in[13];
    const float* b_key   = (const float*)d_in[14];
    const float* W_val   = (const float*)d_in[15];
    const float* b_val   = (const float*)d_in[16];
    const float* W_q     = (const float*)d_in[17];
    const float* b_q     = (const float*)d_in[18];
    const float* W_ih    = (const float*)d_in[19];
    const float* b_ih    = (const float*)d_in[20];
    const float* W_hh    = (const float*)d_in[21];
    const float* b_hh    = (const float*)d_in[22];
    const float* ln_g    = (const float*)d_in[23];
    const float* ln_b    = (const float*)d_in[24];
    const float* W1      = (const float*)d_in[25];
    const float* b1      = (const float*)d_in[26];
    const float* W2      = (const float*)d_in[27];
    const float* b2      = (const float*)d_in[28];
    const float* rms_w   = (const float*)d_in[29];
    const float* lin_w   = (const float*)d_in[30];

    const int N = in_sizes[1];
    const int P = in_sizes[9] / 128;
    const int E = in_sizes[11];
    const int Mpad = ((N + 127) / 128) * 128;   // 100096
    const int Mq   = ((P + 127) / 128) * 128;   // 10112

    // workspace layout (byte offsets, 256B aligned)
    char* base = (char*)d_ws;
    size_t off = 0;
    auto alloc = [&](size_t bytes) { void* p = base + off; off = (off + bytes + 255) & ~(size_t)255; return p; };
    bf16_t* skipb = (bf16_t*)alloc((size_t)Mpad * 32 * 2);
    bf16_t* WbfT  = (bf16_t*)alloc(256 * 288 * 2);
    bf16_t* WqT   = (bf16_t*)alloc(128 * 384 * 2);
    float*  bpn   = (float*)alloc(256 * 4);
    float*  bpq   = (float*)alloc(128 * 4);
    bf16_t* KVb   = (bf16_t*)alloc((size_t)Mpad * 256 * 2);
    bf16_t* Qb    = (bf16_t*)alloc((size_t)Mq * 128 * 2);
    // cnt and cur MUST be contiguous: prep_all zeroes cnt[0..2P)
    int*    cnt   = (int*)alloc((size_t)(2 * P) * 4);
    int*    cur   = cnt + P;
    int*    offb  = (int*)alloc((size_t)(P + 1) * 4);
    int*    csrc  = (int*)alloc((size_t)E * 4);
    bf16_t* AG    = (bf16_t*)alloc((size_t)Mq * 256 * 2);
    bf16_t* BTg   = (bf16_t*)alloc(768 * 256 * 2);
    float*  bgru  = (float*)alloc(768 * 4);
    float*  G768  = (float*)alloc((size_t)Mq * 768 * 4);
    bf16_t* LNb   = (bf16_t*)alloc((size_t)Mq * 128 * 2);

    // 1. merged weight prep (+ cnt zero + AG pad zero) + skip features
    {
        int padElems = (Mq - P) * 256;
        int T1 = 256 * 288 + 128 * 384 + 256 + 128;
        int T2 = 768 * 256 + 768 + 2 * P + padElems;
        prep_all<<<(T1 + T2 + THREADS - 1) / THREADS, THREADS, 0, stream>>>(
            W_key, W_val, W_q, b_key, b_val, b_q, WbfT, WqT, bpn, bpq,
            W_ih, W_hh, b_ih, b_hh, BTg, bgru, cnt, 2 * P, AG, P, padElems);
        skip_kernel<<<(Mpad + THREADS - 1) / THREADS, THREADS, 0, stream>>>(
            energy, eta, phi, layer, eta_l, phi_l, ene_l, track, skipb, N, Mpad);
    }
    // 2. K/V GEMM (pipelined-barrier variant) + Q GEMM
    mfma_gemm<0><<<dim3(2, Mpad / 64), THREADS, 0, stream>>>(
        nh, skipb, WbfT, bpn, KVb, 288, N);
    mfma_gemm<1><<<dim3(1, Mq / 64), THREADS, 0, stream>>>(
        ph, grep, WqT, bpq, Qb, 384, P);
    // 3. CSR build
    hist_kernel<<<(E + THREADS - 1) / THREADS, THREADS, 0, stream>>>(edst, cnt, E);
    scan_kernel<<<1, 1024, 0, stream>>>(cnt, offb, P);
    fill_src_kernel<<<(E + THREADS - 1) / THREADS, THREADS, 0, stream>>>(
        edst, esrc, offb, cur, csrc, E);
    // 4. fused attention + gather + gate -> AG
    edge_kernel<<<(P + 3) / 4, THREADS, 0, stream>>>(
        offb, csrc, KVb, Qb, ph, rms_w, lin_w, AG, P);
    // 5. node update: GRU GEMM -> GRU/LN pointwise -> fused MLP+residual
    mfma_gemm<2><<<dim3(6, Mq / 64), THREADS, 0, stream>>>(
        AG, nullptr, BTg, bgru, G768, 256, Mq);
    gru_ln_kernel<<<Mq / 16, THREADS, 0, stream>>>(G768, ph, ln_g, ln_b, LNb, P, Mq);
    mlp_kernel<<<Mq / 16, THREADS, 0, stream>>>(LNb, ph, W1, b1, W2, b2, (float*)d_out, P);
}

// Round 17
// 224.943 us; speedup vs baseline: 1.1608x; 1.0281x over previous
//
#include <hip/hip_runtime.h>
#include <hip/hip_bf16.h>
#include <math.h>

#define THREADS 256

typedef __bf16 bf16_t;
typedef __bf16 bf16x8 __attribute__((ext_vector_type(8)));
typedef float f32x4 __attribute__((ext_vector_type(4)));

__device__ __forceinline__ float sigmoidf_(float x) { return 1.f / (1.f + expf(-x)); }

__device__ __forceinline__ void gload_lds16(const void* g, void* l) {
    __builtin_amdgcn_global_load_lds((const __attribute__((address_space(1))) void*)g,
                                     (__attribute__((address_space(3))) void*)l, 16, 0, 0);
}

__device__ __forceinline__ bf16x8 cvt8(float4 a, float4 b) {
    bf16x8 v;
    v[0] = (bf16_t)a.x; v[1] = (bf16_t)a.y; v[2] = (bf16_t)a.z; v[3] = (bf16_t)a.w;
    v[4] = (bf16_t)b.x; v[5] = (bf16_t)b.y; v[6] = (bf16_t)b.z; v[7] = (bf16_t)b.w;
    return v;
}

// ------------------------------------------------------------------
// prep_all: merged weight prep (best-measured r13 config).
// [0,T1): WbfT [256][288], WqT [128][384], bpn[256], bpq[128].
// [T1,..): BTg [768][256], W1Tp, W2Tp, bgru, b1p, cnt zero, AG pad zero.
// ------------------------------------------------------------------
__global__ void prep_all(const float* __restrict__ W_key, const float* __restrict__ W_val,
                         const float* __restrict__ W_q, const float* __restrict__ b_key,
                         const float* __restrict__ b_val, const float* __restrict__ b_q,
                         bf16_t* __restrict__ WbfT, bf16_t* __restrict__ WqT,
                         float* __restrict__ bpn, float* __restrict__ bpq,
                         const float* __restrict__ W_ih, const float* __restrict__ W_hh,
                         const float* __restrict__ b_ih, const float* __restrict__ b_hh,
                         const float* __restrict__ W1, const float* __restrict__ b1,
                         const float* __restrict__ W2,
                         bf16_t* __restrict__ BTg, bf16_t* __restrict__ W1Tp,
                         bf16_t* __restrict__ W2Tp, float* __restrict__ bgru,
                         float* __restrict__ b1p,
                         int* __restrict__ cnt, int twoP,
                         bf16_t* __restrict__ AG, int padStart, int padElems)
{
    int i0 = blockIdx.x * THREADS + threadIdx.x;
    const int NW = 256 * 288, NQ = 128 * 384;
    const int T1 = NW + NQ + 256 + 128;
    if (i0 < T1) {
        int i = i0;
        if (i < NW) {
            int c = i / 288, k = i - c * 288;
            float v = 0.f;
            if (k < 283) {
                if (c < 100) v = W_key[k * 100 + c];
                else if (c >= 128 && c < 256) v = W_val[k * 128 + (c - 128)];
            }
            WbfT[i] = (bf16_t)v;
        } else if (i < NW + NQ) {
            int j = i - NW;
            int c = j / 384, k = j - c * 384;
            WqT[j] = (bf16_t)((c < 100) ? W_q[k * 100 + c] : 0.f);
        } else if (i < NW + NQ + 256) {
            int c = i - NW - NQ;
            bpn[c] = (c < 100) ? b_key[c] : ((c >= 128 && c < 256) ? b_val[c - 128] : 0.f);
        } else {
            int c = i - NW - NQ - 256;
            bpq[c] = (c < 100) ? b_q[c] : 0.f;
        }
        return;
    }
    int i = i0 - T1;
    const int NG = 768 * 256, N1 = 128 * 128, N2 = 128 * 128;
    const int NB = NG + N1 + N2 + 768 + 128;
    if (i < NG) {
        int c = i >> 8, k = i & 255;
        float v = 0.f;
        if (c < 384) { if (k < 128) v = W_ih[k * 384 + c]; }
        else         { if (k >= 128) v = W_hh[(k - 128) * 384 + (c - 384)]; }
        BTg[i] = (bf16_t)v;
    } else if (i < NG + N1) {
        int j = i - NG; int c = j >> 7, k = j & 127;
        W1Tp[j] = (bf16_t)((c < 64) ? W1[k * 64 + c] : 0.f);
    } else if (i < NG + N1 + N2) {
        int j = i - NG - N1; int c = j >> 7, k = j & 127;
        W2Tp[j] = (bf16_t)((k < 64) ? W2[k * 128 + c] : 0.f);
    } else if (i < NG + N1 + N2 + 768) {
        int c = i - NG - N1 - N2;
        bgru[c] = (c < 384) ? b_ih[c] : b_hh[c - 384];
    } else if (i < NB) {
        int c = i - NG - N1 - N2 - 768;
        b1p[c] = (c < 64) ? b1[c] : 0.f;
    } else if (i < NB + twoP) {
        cnt[i - NB] = 0;
    } else if (i < NB + twoP + padElems) {
        int j = i - NB - twoP;
        AG[(size_t)padStart * 256 + j] = (bf16_t)0.f;
    }
}

// skip features -> skipb bf16 [Mpad,32] (27 real + 5 zero; pad rows zero)
__global__ void skip_kernel(const float* __restrict__ energy, const float* __restrict__ eta,
                            const float* __restrict__ phi, const float* __restrict__ layer,
                            const float* __restrict__ eta_l, const float* __restrict__ phi_l,
                            const float* __restrict__ ene_l, const float* __restrict__ track,
                            bf16_t* __restrict__ skipb, int N_, int Mpad)
{
    int n = blockIdx.x * THREADS + threadIdx.x;
    if (n >= Mpad) return;
    float o[32];
#pragma unroll
    for (int j = 0; j < 32; ++j) o[j] = 0.f;
    if (n < N_) {
        o[0] = (logf(energy[n]) - 4.0f) * 0.5f;
        o[1] = eta[n] * (1.f / 1.5f);
        o[2] = phi[n];
        o[3] = layer[n];
#pragma unroll
        for (int j = 0; j < 6; ++j) o[4 + j]  = eta_l[n * 6 + j] * (1.f / 1.5f);
#pragma unroll
        for (int j = 0; j < 6; ++j) o[10 + j] = phi_l[n * 6 + j];
#pragma unroll
        for (int j = 0; j < 6; ++j) o[16 + j] = ene_l[n * 6 + j];
#pragma unroll
        for (int j = 0; j < 5; ++j) o[22 + j] = track[n * 5 + j];
    }
    bf16_t* dst = skipb + (size_t)n * 32;
#pragma unroll
    for (int g = 0; g < 4; ++g) {
        bf16x8 v;
#pragma unroll
        for (int j = 0; j < 8; ++j) v[j] = (bf16_t)o[g * 8 + j];
        *(bf16x8*)(dst + g * 8) = v;
    }
}

// ------------------------------------------------------------------
// bf16 MFMA GEMM: 64x128 tile, BK=32, 4 waves (32x64 each), single-
// buffered 12KB LDS, 2-barrier loop — the empirically-best structure.
// MODE 0: A = nh fp32 [.,256] | skipb bf16 [.,32]; K=288; out KVb ldc256
// MODE 1: A = ph fp32 [.,128] | grep fp32 [.,256]; K=384; out Qb bf16
// MODE 2: A bf16 stride K; fp32 out ldc=768   MODE 3: bf16 out + relu
// MODE 4: fp32 out = acc+bias+resid, row<Mlimit
// ------------------------------------------------------------------
template <int MODE>
__global__ __launch_bounds__(256) void mfma_gemm(
    const void* __restrict__ A0, const void* __restrict__ A1,
    const bf16_t* __restrict__ BT, const float* __restrict__ bias,
    void* __restrict__ out0v, const float* __restrict__ resid,
    int K, int Mlimit, int Nrows)
{
    __shared__ short AsS[64 * 32];   // [row][k] bf16, 64B rows
    __shared__ short BsS[128 * 32];  // [col][k]
    int tid = threadIdx.x;
    int lane = tid & 63, w = tid >> 6;
    int la = lane & 15, hi = lane >> 4;
    int m0 = (w & 1) * 32, n0 = (w >> 1) * 64;
    int row0 = blockIdx.y * 64, col0 = blockIdx.x * 128;

    f32x4 zero4 = {0.f, 0.f, 0.f, 0.f};
    f32x4 acc[2][4];
#pragma unroll
    for (int i = 0; i < 2; ++i)
#pragma unroll
        for (int j = 0; j < 4; ++j) acc[i][j] = zero4;

    const int ra = tid >> 2, ka = (tid & 3) * 8;   // A: 1 chunk (16B) / thread
    const int c1 = tid + 256;                       // B: 2 chunks / thread
    const int rb0 = tid >> 2, kb0 = (tid & 3) * 8;
    const int rb1 = c1 >> 2,  kb1 = (c1 & 3) * 8;

    for (int kt = 0; kt < K; kt += 32) {
        int gmA = row0 + ra;
        if (MODE == 0) {
            if (kt < 256) {  // kt uniform -> no divergence
                bf16x8 v = {};
                if (gmA < Nrows) {
                    const float* s = (const float*)A0 + (size_t)gmA * 256 + kt + ka;
                    v = cvt8(*(const float4*)s, *(const float4*)(s + 4));
                }
                *(bf16x8*)(AsS + (size_t)tid * 8) = v;
            } else {
                gload_lds16((const bf16_t*)A1 + (size_t)gmA * 32 + (kt - 256) + ka,
                            AsS + (size_t)tid * 8);
            }
        } else if (MODE == 1) {
            int gk = kt + ka;
            bf16x8 v = {};
            if (gmA < Nrows) {
                const float* s = (gk < 128) ? ((const float*)A0 + (size_t)gmA * 128 + gk)
                                            : ((const float*)A1 + (size_t)gmA * 256 + (gk - 128));
                v = cvt8(*(const float4*)s, *(const float4*)(s + 4));
            }
            *(bf16x8*)(AsS + (size_t)tid * 8) = v;
        } else {
            gload_lds16((const bf16_t*)A0 + (size_t)gmA * K + kt + ka,
                        AsS + (size_t)tid * 8);
        }
        gload_lds16(BT + (size_t)(col0 + rb0) * K + kt + kb0, BsS + (size_t)tid * 8);
        gload_lds16(BT + (size_t)(col0 + rb1) * K + kt + kb1, BsS + (size_t)c1 * 8);
        __syncthreads();
        bf16x8 a[2], b[4];
#pragma unroll
        for (int i = 0; i < 2; ++i)
            a[i] = *(const bf16x8*)(AsS + (m0 + i * 16 + la) * 32 + hi * 8);
#pragma unroll
        for (int j = 0; j < 4; ++j)
            b[j] = *(const bf16x8*)(BsS + (n0 + j * 16 + la) * 32 + hi * 8);
#pragma unroll
        for (int i = 0; i < 2; ++i)
#pragma unroll
            for (int j = 0; j < 4; ++j)
                acc[i][j] = __builtin_amdgcn_mfma_f32_16x16x32_bf16(a[i], b[j], acc[i][j], 0, 0, 0);
        __syncthreads();
    }

#pragma unroll
    for (int i = 0; i < 2; ++i) {
#pragma unroll
        for (int j = 0; j < 4; ++j) {
            int col = col0 + n0 + j * 16 + la;
            float bb = bias[col];
#pragma unroll
            for (int r = 0; r < 4; ++r) {
                int row = row0 + m0 + i * 16 + hi * 4 + r;
                float v = acc[i][j][r] + bb;
                if (MODE == 0) {
                    ((bf16_t*)out0v)[(size_t)row * 256 + col] = (bf16_t)v;  // KVb interleaved
                } else if (MODE == 1) {
                    ((bf16_t*)out0v)[(size_t)row * 128 + col] = (bf16_t)v;
                } else if (MODE == 2) {
                    ((float*)out0v)[(size_t)row * 768 + col] = v;
                } else if (MODE == 3) {
                    ((bf16_t*)out0v)[(size_t)row * 128 + col] = (bf16_t)fmaxf(v, 0.f);
                } else {  // MODE 4
                    if (row < Mlimit)
                        ((float*)out0v)[(size_t)row * 128 + col] = v + resid[(size_t)row * 128 + col];
                }
            }
        }
    }
}

// ------------------------------------------------------------------
// CSR build (cnt zeroed by prep_all)
// ------------------------------------------------------------------
__global__ void hist_kernel(const int* __restrict__ dst, int* __restrict__ cnt, int E_)
{
    int i = blockIdx.x * THREADS + threadIdx.x;
    if (i < E_) atomicAdd(&cnt[dst[i]], 1);
}

__global__ void scan_kernel(const int* __restrict__ cnt, int* __restrict__ offb, int P_)
{
    __shared__ int wsum[16];
    int tid = threadIdx.x;
    int lane = tid & 63, w = tid >> 6;
    int base = tid * 10;
    int c[10];
    int s = 0;
#pragma unroll
    for (int j = 0; j < 10; ++j) {
        int i = base + j;
        c[j] = (i < P_) ? cnt[i] : 0;
        s += c[j];
    }
    int pre = s;
    for (int o = 1; o < 64; o <<= 1) {
        int t = __shfl_up(pre, o);
        if (lane >= o) pre += t;
    }
    if (lane == 63) wsum[w] = pre;
    __syncthreads();
    if (w == 0 && lane < 16) {
        int v = wsum[lane];
        for (int o = 1; o < 16; o <<= 1) {
            int t = __shfl_up(v, o, 16);
            if (lane >= o) v += t;
        }
        wsum[lane] = v;
    }
    __syncthreads();
    int waveoff = (w == 0) ? 0 : wsum[w - 1];
    int run = waveoff + pre - s;
#pragma unroll
    for (int j = 0; j < 10; ++j) {
        int i = base + j;
        if (i <= P_) offb[i] = run;
        run += c[j];
    }
}

__global__ void fill_src_kernel(const int* __restrict__ dst, const int* __restrict__ src,
                                const int* __restrict__ offb, int* __restrict__ cur,
                                int* __restrict__ csrc, int E_)
{
    int i = blockIdx.x * THREADS + threadIdx.x;
    if (i < E_) {
        int d = dst[i];
        int pos = atomicAdd(&cur[d], 1);
        csrc[offb[d] + pos] = src[i];
    }
}

// ------------------------------------------------------------------
// fused attention + gather + rms/sigmoid gate: 1 wave/particle, 4/block.
// lane = (g=lane>>4 edge-group, c=lane&15 col-chunk). KVb row: K 0..127,
// V 128..255. After cross-group reduce, all lanes hold the row sums ->
// gate computed in-register, AG = [gated | h] bf16 written directly.
// ------------------------------------------------------------------
__global__ __launch_bounds__(256) void edge_kernel(
    const int* __restrict__ offb, const int* __restrict__ csrc,
    const bf16_t* __restrict__ KVb, const bf16_t* __restrict__ Qb,
    const float* __restrict__ ph, const float* __restrict__ rms_w,
    const float* __restrict__ lin_w, bf16_t* __restrict__ AG, int P_)
{
    int tid = threadIdx.x;
    int p = blockIdx.x * 4 + (tid >> 6);
    if (p >= P_) return;
    int lane = tid & 63;
    int c = lane & 15, g = lane >> 4;

    bf16x8 q8 = *(const bf16x8*)(Qb + (size_t)p * 128 + c * 8);
    float qf[8];
#pragma unroll
    for (int j = 0; j < 8; ++j) qf[j] = (float)q8[j];

    int s0 = offb[p], e0 = offb[p + 1];
    float acc[8] = {};

    int i = s0 + g;
    for (; i + 12 < e0; i += 16) {
        int n0 = csrc[i], n1 = csrc[i + 4], n2 = csrc[i + 8], n3 = csrc[i + 12];
        const bf16_t* b0 = KVb + (size_t)n0 * 256 + c * 8;
        const bf16_t* b1 = KVb + (size_t)n1 * 256 + c * 8;
        const bf16_t* b2 = KVb + (size_t)n2 * 256 + c * 8;
        const bf16_t* b3 = KVb + (size_t)n3 * 256 + c * 8;
        bf16x8 k0 = *(const bf16x8*)b0, v0 = *(const bf16x8*)(b0 + 128);
        bf16x8 k1 = *(const bf16x8*)b1, v1 = *(const bf16x8*)(b1 + 128);
        bf16x8 k2 = *(const bf16x8*)b2, v2 = *(const bf16x8*)(b2 + 128);
        bf16x8 k3 = *(const bf16x8*)b3, v3 = *(const bf16x8*)(b3 + 128);
        float d0 = 0.f, d1 = 0.f, d2 = 0.f, d3 = 0.f;
#pragma unroll
        for (int j = 0; j < 8; ++j) {
            d0 += qf[j] * (float)k0[j]; d1 += qf[j] * (float)k1[j];
            d2 += qf[j] * (float)k2[j]; d3 += qf[j] * (float)k3[j];
        }
        d0 += __shfl_xor(d0, 1); d1 += __shfl_xor(d1, 1); d2 += __shfl_xor(d2, 1); d3 += __shfl_xor(d3, 1);
        d0 += __shfl_xor(d0, 2); d1 += __shfl_xor(d1, 2); d2 += __shfl_xor(d2, 2); d3 += __shfl_xor(d3, 2);
        d0 += __shfl_xor(d0, 4); d1 += __shfl_xor(d1, 4); d2 += __shfl_xor(d2, 4); d3 += __shfl_xor(d3, 4);
        d0 += __shfl_xor(d0, 8); d1 += __shfl_xor(d1, 8); d2 += __shfl_xor(d2, 8); d3 += __shfl_xor(d3, 8);
        float a0 = fmaxf(d0 * 0.1f, 0.f), a1 = fmaxf(d1 * 0.1f, 0.f);
        float a2 = fmaxf(d2 * 0.1f, 0.f), a3 = fmaxf(d3 * 0.1f, 0.f);
#pragma unroll
        for (int j = 0; j < 8; ++j)
            acc[j] += a0 * (float)v0[j] + a1 * (float)v1[j]
                    + a2 * (float)v2[j] + a3 * (float)v3[j];
    }
    for (; i < e0; i += 4) {
        int nA = csrc[i];
        const bf16_t* bA = KVb + (size_t)nA * 256 + c * 8;
        bf16x8 kA = *(const bf16x8*)bA;
        bf16x8 vA = *(const bf16x8*)(bA + 128);
        float dA = 0.f;
#pragma unroll
        for (int j = 0; j < 8; ++j) dA += qf[j] * (float)kA[j];
        dA += __shfl_xor(dA, 1);
        dA += __shfl_xor(dA, 2);
        dA += __shfl_xor(dA, 4);
        dA += __shfl_xor(dA, 8);
        float aA = fmaxf(dA * 0.1f, 0.f);
#pragma unroll
        for (int j = 0; j < 8; ++j) acc[j] += aA * (float)vA[j];
    }

    // reduce across the 4 edge-groups; afterwards every lane holds totals
#pragma unroll
    for (int j = 0; j < 8; ++j) {
        acc[j] += __shfl_xor(acc[j], 16);
        acc[j] += __shfl_xor(acc[j], 32);
    }

    // fused rms-norm * sigmoid gate
    float ss = 0.f;
#pragma unroll
    for (int j = 0; j < 8; ++j) ss += acc[j] * acc[j];
    ss += __shfl_xor(ss, 1); ss += __shfl_xor(ss, 2); ss += __shfl_xor(ss, 4); ss += __shfl_xor(ss, 8);
    float scale = rsqrtf(ss * (1.f / 128.f) + 1e-6f);
    if (g == 0) {
        int cb = c * 8;
        const float* hp = ph + (size_t)p * 128 + cb;
        float4 ha = *(const float4*)hp, hb = *(const float4*)(hp + 4);
        float hv[8] = {ha.x, ha.y, ha.z, ha.w, hb.x, hb.y, hb.z, hb.w};
        bf16x8 gv, hvb;
#pragma unroll
        for (int j = 0; j < 8; ++j) {
            float wsv = acc[j];
            float rv = wsv * scale * rms_w[cb + j];
            gv[j] = (bf16_t)(rv * sigmoidf_(wsv * lin_w[cb + j]));
            hvb[j] = (bf16_t)hv[j];
        }
        *(bf16x8*)(AG + (size_t)p * 256 + cb) = gv;
        *(bf16x8*)(AG + (size_t)p * 256 + 128 + cb) = hvb;
    }
}

// ------------------------------------------------------------------
// gru+ln pointwise: G768 fp32 (gi|gh) -> h_new -> LN -> LNb bf16
// ------------------------------------------------------------------
__global__ void gru_ln_kernel(const float* __restrict__ G768, const float* __restrict__ ph,
                              const float* __restrict__ ln_g, const float* __restrict__ ln_b,
                              bf16_t* __restrict__ LNb, int P_, int Mq)
{
    int tid = threadIdx.x;
    int g = tid >> 4, s = tid & 15;
    int p = blockIdx.x * 16 + g;
    if (p >= Mq) return;
    int cb = s * 8;
    if (p >= P_) {
        bf16x8 z = {};
        *(bf16x8*)(LNb + (size_t)p * 128 + cb) = z;
        return;
    }
    const float* G = G768 + (size_t)p * 768;
    float ir[8], iz[8], in_[8], hr[8], hz[8], hn_[8], hv[8];
#pragma unroll
    for (int q = 0; q < 2; ++q) {
        float4 v;
        v = *(const float4*)(G + cb + q * 4);        ir[q*4]=v.x; ir[q*4+1]=v.y; ir[q*4+2]=v.z; ir[q*4+3]=v.w;
        v = *(const float4*)(G + 128 + cb + q * 4);  iz[q*4]=v.x; iz[q*4+1]=v.y; iz[q*4+2]=v.z; iz[q*4+3]=v.w;
        v = *(const float4*)(G + 256 + cb + q * 4);  in_[q*4]=v.x; in_[q*4+1]=v.y; in_[q*4+2]=v.z; in_[q*4+3]=v.w;
        v = *(const float4*)(G + 384 + cb + q * 4);  hr[q*4]=v.x; hr[q*4+1]=v.y; hr[q*4+2]=v.z; hr[q*4+3]=v.w;
        v = *(const float4*)(G + 512 + cb + q * 4);  hz[q*4]=v.x; hz[q*4+1]=v.y; hz[q*4+2]=v.z; hz[q*4+3]=v.w;
        v = *(const float4*)(G + 640 + cb + q * 4);  hn_[q*4]=v.x; hn_[q*4+1]=v.y; hn_[q*4+2]=v.z; hn_[q*4+3]=v.w;
        v = *(const float4*)(ph + (size_t)p * 128 + cb + q * 4);
        hv[q*4]=v.x; hv[q*4+1]=v.y; hv[q*4+2]=v.z; hv[q*4+3]=v.w;
    }
    float hn[8];
    float sm = 0.f, sq = 0.f;
#pragma unroll
    for (int j = 0; j < 8; ++j) {
        float r = sigmoidf_(ir[j] + hr[j]);
        float z = sigmoidf_(iz[j] + hz[j]);
        float n = tanhf(in_[j] + r * hn_[j]);
        hn[j] = (1.f - z) * n + z * hv[j];
        sm += hn[j]; sq += hn[j] * hn[j];
    }
    sm += __shfl_xor(sm, 1); sm += __shfl_xor(sm, 2); sm += __shfl_xor(sm, 4); sm += __shfl_xor(sm, 8);
    sq += __shfl_xor(sq, 1); sq += __shfl_xor(sq, 2); sq += __shfl_xor(sq, 4); sq += __shfl_xor(sq, 8);
    float mu = sm * (1.f / 128.f);
    float var = sq * (1.f / 128.f) - mu * mu;
    float iv = rsqrtf(var + 1e-5f);
    bf16x8 o;
#pragma unroll
    for (int j = 0; j < 8; ++j) {
        int c = cb + j;
        o[j] = (bf16_t)((hn[j] - mu) * iv * ln_g[c] + ln_b[c]);
    }
    *(bf16x8*)(LNb + (size_t)p * 128 + cb) = o;
}

// ------------------------------------------------------------------
extern "C" void kernel_launch(void* const* d_in, const int* in_sizes, int n_in,
                              void* d_out, int out_size, void* d_ws, size_t ws_size,
                              hipStream_t stream)
{
    const float* nh      = (const float*)d_in[0];
    const float* energy  = (const float*)d_in[1];
    const float* eta     = (const float*)d_in[2];
    const float* phi     = (const float*)d_in[3];
    const float* layer   = (const float*)d_in[4];
    const float* eta_l   = (const float*)d_in[5];
    const float* phi_l   = (const float*)d_in[6];
    const float* ene_l   = (const float*)d_in[7];
    const float* track   = (const float*)d_in[8];
    const float* ph      = (const float*)d_in[9];
    const float* grep    = (const float*)d_in[10];
    const int*   esrc    = (const int*)d_in[11];
    const int*   edst    = (const int*)d_in[12];
    const float* W_key   = (const float*)d_in[13];
    const float* b_key   = (const float*)d_in[14];
    const float* W_val   = (const float*)d_in[15];
    const float* b_val   = (const float*)d_in[16];
    const float* W_q     = (const float*)d_in[17];
    const float* b_q     = (const float*)d_in[18];
    const float* W_ih    = (const float*)d_in[19];
    const float* b_ih    = (const float*)d_in[20];
    const float* W_hh    = (const float*)d_in[21];
    const float* b_hh    = (const float*)d_in[22];
    const float* ln_g    = (const float*)d_in[23];
    const float* ln_b    = (const float*)d_in[24];
    const float* W1      = (const float*)d_in[25];
    const float* b1      = (const float*)d_in[26];
    const float* W2      = (const float*)d_in[27];
    const float* b2      = (const float*)d_in[28];
    const float* rms_w   = (const float*)d_in[29];
    const float* lin_w   = (const float*)d_in[30];

    const int N = in_sizes[1];
    const int P = in_sizes[9] / 128;
    const int E = in_sizes[11];
    const int Mpad = ((N + 127) / 128) * 128;   // 100096
    const int Mq   = ((P + 127) / 128) * 128;   // 10112

    // workspace layout (byte offsets, 256B aligned)
    char* base = (char*)d_ws;
    size_t off = 0;
    auto alloc = [&](size_t bytes) { void* p = base + off; off = (off + bytes + 255) & ~(size_t)255; return p; };
    bf16_t* skipb = (bf16_t*)alloc((size_t)Mpad * 32 * 2);
    bf16_t* WbfT  = (bf16_t*)alloc(256 * 288 * 2);
    bf16_t* WqT   = (bf16_t*)alloc(128 * 384 * 2);
    float*  bpn   = (float*)alloc(256 * 4);
    float*  bpq   = (float*)alloc(128 * 4);
    bf16_t* KVb   = (bf16_t*)alloc((size_t)Mpad * 256 * 2);
    bf16_t* Qb    = (bf16_t*)alloc((size_t)Mq * 128 * 2);
    // cnt and cur MUST be contiguous: prep_all zeroes cnt[0..2P)
    int*    cnt   = (int*)alloc((size_t)(2 * P) * 4);
    int*    cur   = cnt + P;
    int*    offb  = (int*)alloc((size_t)(P + 1) * 4);
    int*    csrc  = (int*)alloc((size_t)E * 4);
    bf16_t* AG    = (bf16_t*)alloc((size_t)Mq * 256 * 2);
    bf16_t* BTg   = (bf16_t*)alloc(768 * 256 * 2);
    bf16_t* W1Tp  = (bf16_t*)alloc(128 * 128 * 2);
    bf16_t* W2Tp  = (bf16_t*)alloc(128 * 128 * 2);
    float*  bgru  = (float*)alloc(768 * 4);
    float*  b1p   = (float*)alloc(128 * 4);
    float*  G768  = (float*)alloc((size_t)Mq * 768 * 4);
    bf16_t* LNb   = (bf16_t*)alloc((size_t)Mq * 128 * 2);
    bf16_t* M1    = (bf16_t*)alloc((size_t)Mq * 128 * 2);

    // 1. merged weight prep (+ cnt zero + AG pad zero) + skip features
    {
        int padElems = (Mq - P) * 256;
        int T1 = 256 * 288 + 128 * 384 + 256 + 128;
        int T2 = 768 * 256 + 128 * 128 + 128 * 128 + 768 + 128 + 2 * P + padElems;
        prep_all<<<(T1 + T2 + THREADS - 1) / THREADS, THREADS, 0, stream>>>(
            W_key, W_val, W_q, b_key, b_val, b_q, WbfT, WqT, bpn, bpq,
            W_ih, W_hh, b_ih, b_hh, W1, b1, W2, BTg, W1Tp, W2Tp, bgru, b1p,
            cnt, 2 * P, AG, P, padElems);
        skip_kernel<<<(Mpad + THREADS - 1) / THREADS, THREADS, 0, stream>>>(
            energy, eta, phi, layer, eta_l, phi_l, ene_l, track, skipb, N, Mpad);
    }
    // 2. K/V GEMM (r8/r13 structure, measured best) + Q GEMM
    mfma_gemm<0><<<dim3(2, Mpad / 64), THREADS, 0, stream>>>(
        nh, skipb, WbfT, bpn, KVb, nullptr, 288, 0, N);
    mfma_gemm<1><<<dim3(1, Mq / 64), THREADS, 0, stream>>>(
        ph, grep, WqT, bpq, Qb, nullptr, 384, 0, P);
    // 3. CSR build (src ids stored directly)
    hist_kernel<<<(E + THREADS - 1) / THREADS, THREADS, 0, stream>>>(edst, cnt, E);
    scan_kernel<<<1, 1024, 0, stream>>>(cnt, offb, P);
    fill_src_kernel<<<(E + THREADS - 1) / THREADS, THREADS, 0, stream>>>(
        edst, esrc, offb, cur, csrc, E);
    // 4. fused attention + gather + gate -> AG
    edge_kernel<<<(P + 3) / 4, THREADS, 0, stream>>>(
        offb, csrc, KVb, Qb, ph, rms_w, lin_w, AG, P);
    // 5. node update: GRU GEMM -> pointwise+LN -> MLP1 -> MLP2+residual
    mfma_gemm<2><<<dim3(6, Mq / 64), THREADS, 0, stream>>>(
        AG, nullptr, BTg, bgru, G768, nullptr, 256, 0, Mq);
    gru_ln_kernel<<<Mq / 16, THREADS, 0, stream>>>(G768, ph, ln_g, ln_b, LNb, P, Mq);
    mfma_gemm<3><<<dim3(1, Mq / 64), THREADS, 0, stream>>>(
        LNb, nullptr, W1Tp, b1p, M1, nullptr, 128, 0, Mq);
    mfma_gemm<4><<<dim3(1, Mq / 64), THREADS, 0, stream>>>(
        M1, nullptr, W2Tp, b2, d_out, ph, 128, P, Mq);
}

// Round 18
// 221.889 us; speedup vs baseline: 1.1768x; 1.0138x over previous
//
#include <hip/hip_runtime.h>
#include <hip/hip_bf16.h>
#include <math.h>

#define THREADS 256

typedef __bf16 bf16_t;
typedef __bf16 bf16x8 __attribute__((ext_vector_type(8)));
typedef float f32x4 __attribute__((ext_vector_type(4)));

__device__ __forceinline__ float sigmoidf_(float x) { return 1.f / (1.f + expf(-x)); }

__device__ __forceinline__ void gload_lds16(const void* g, void* l) {
    __builtin_amdgcn_global_load_lds((const __attribute__((address_space(1))) void*)g,
                                     (__attribute__((address_space(3))) void*)l, 16, 0, 0);
}

__device__ __forceinline__ bf16x8 cvt8(float4 a, float4 b) {
    bf16x8 v;
    v[0] = (bf16_t)a.x; v[1] = (bf16_t)a.y; v[2] = (bf16_t)a.z; v[3] = (bf16_t)a.w;
    v[4] = (bf16_t)b.x; v[5] = (bf16_t)b.y; v[6] = (bf16_t)b.z; v[7] = (bf16_t)b.w;
    return v;
}

// ------------------------------------------------------------------
// prep_all: merged weight prep.
// [0,T1): WbfT [256][288], WqT [128][384], bpn[256], bpq[128].
// [T1,..): BTg [512][256] (r/z fold: col c<256 = [W_ih[:,c];W_hh[:,c]]
//          -> acc = i_rz + h_rz; cols 256-383 = [W_ih[:,256+c'];0] = i_n;
//          cols 384-511 = [0;W_hh[:,256+c']] = h_n), W1Tp, W2Tp,
//          bgru[512], b1p, cnt zero, AG pad zero.
// ------------------------------------------------------------------
__global__ void prep_all(const float* __restrict__ W_key, const float* __restrict__ W_val,
                         const float* __restrict__ W_q, const float* __restrict__ b_key,
                         const float* __restrict__ b_val, const float* __restrict__ b_q,
                         bf16_t* __restrict__ WbfT, bf16_t* __restrict__ WqT,
                         float* __restrict__ bpn, float* __restrict__ bpq,
                         const float* __restrict__ W_ih, const float* __restrict__ W_hh,
                         const float* __restrict__ b_ih, const float* __restrict__ b_hh,
                         const float* __restrict__ W1, const float* __restrict__ b1,
                         const float* __restrict__ W2,
                         bf16_t* __restrict__ BTg, bf16_t* __restrict__ W1Tp,
                         bf16_t* __restrict__ W2Tp, float* __restrict__ bgru,
                         float* __restrict__ b1p,
                         int* __restrict__ cnt, int twoP,
                         bf16_t* __restrict__ AG, int padStart, int padElems)
{
    int i0 = blockIdx.x * THREADS + threadIdx.x;
    const int NW = 256 * 288, NQ = 128 * 384;
    const int T1 = NW + NQ + 256 + 128;
    if (i0 < T1) {
        int i = i0;
        if (i < NW) {
            int c = i / 288, k = i - c * 288;
            float v = 0.f;
            if (k < 283) {
                if (c < 100) v = W_key[k * 100 + c];
                else if (c >= 128 && c < 256) v = W_val[k * 128 + (c - 128)];
            }
            WbfT[i] = (bf16_t)v;
        } else if (i < NW + NQ) {
            int j = i - NW;
            int c = j / 384, k = j - c * 384;
            WqT[j] = (bf16_t)((c < 100) ? W_q[k * 100 + c] : 0.f);
        } else if (i < NW + NQ + 256) {
            int c = i - NW - NQ;
            bpn[c] = (c < 100) ? b_key[c] : ((c >= 128 && c < 256) ? b_val[c - 128] : 0.f);
        } else {
            int c = i - NW - NQ - 256;
            bpq[c] = (c < 100) ? b_q[c] : 0.f;
        }
        return;
    }
    int i = i0 - T1;
    const int NG = 512 * 256, N1 = 128 * 128, N2 = 128 * 128;
    const int NB = NG + N1 + N2 + 512 + 128;
    if (i < NG) {
        int c = i >> 8, k = i & 255;   // col c of 512, k of 256 ([gated|h])
        float v = 0.f;
        if (c < 256) {
            // fused r/z columns: both halves active
            v = (k < 128) ? W_ih[k * 384 + c] : W_hh[(k - 128) * 384 + c];
        } else if (c < 384) {
            if (k < 128) v = W_ih[k * 384 + (c - 256) + 256];   // i_n
        } else {
            if (k >= 128) v = W_hh[(k - 128) * 384 + (c - 384) + 256];  // h_n
        }
        BTg[i] = (bf16_t)v;
    } else if (i < NG + N1) {
        int j = i - NG; int c = j >> 7, k = j & 127;
        W1Tp[j] = (bf16_t)((c < 64) ? W1[k * 64 + c] : 0.f);
    } else if (i < NG + N1 + N2) {
        int j = i - NG - N1; int c = j >> 7, k = j & 127;
        W2Tp[j] = (bf16_t)((k < 64) ? W2[k * 128 + c] : 0.f);
    } else if (i < NG + N1 + N2 + 512) {
        int c = i - NG - N1 - N2;
        float v;
        if (c < 256)      v = b_ih[c] + b_hh[c];          // r/z fused bias
        else if (c < 384) v = b_ih[(c - 256) + 256];      // i_n bias
        else              v = b_hh[(c - 384) + 256];      // h_n bias
        bgru[c] = v;
    } else if (i < NB) {
        int c = i - NG - N1 - N2 - 512;
        b1p[c] = (c < 64) ? b1[c] : 0.f;
    } else if (i < NB + twoP) {
        cnt[i - NB] = 0;
    } else if (i < NB + twoP + padElems) {
        int j = i - NB - twoP;
        AG[(size_t)padStart * 256 + j] = (bf16_t)0.f;
    }
}

// skip features -> skipb bf16 [Mpad,32] (27 real + 5 zero; pad rows zero)
__global__ void skip_kernel(const float* __restrict__ energy, const float* __restrict__ eta,
                            const float* __restrict__ phi, const float* __restrict__ layer,
                            const float* __restrict__ eta_l, const float* __restrict__ phi_l,
                            const float* __restrict__ ene_l, const float* __restrict__ track,
                            bf16_t* __restrict__ skipb, int N_, int Mpad)
{
    int n = blockIdx.x * THREADS + threadIdx.x;
    if (n >= Mpad) return;
    float o[32];
#pragma unroll
    for (int j = 0; j < 32; ++j) o[j] = 0.f;
    if (n < N_) {
        o[0] = (logf(energy[n]) - 4.0f) * 0.5f;
        o[1] = eta[n] * (1.f / 1.5f);
        o[2] = phi[n];
        o[3] = layer[n];
#pragma unroll
        for (int j = 0; j < 6; ++j) o[4 + j]  = eta_l[n * 6 + j] * (1.f / 1.5f);
#pragma unroll
        for (int j = 0; j < 6; ++j) o[10 + j] = phi_l[n * 6 + j];
#pragma unroll
        for (int j = 0; j < 6; ++j) o[16 + j] = ene_l[n * 6 + j];
#pragma unroll
        for (int j = 0; j < 5; ++j) o[22 + j] = track[n * 5 + j];
    }
    bf16_t* dst = skipb + (size_t)n * 32;
#pragma unroll
    for (int g = 0; g < 4; ++g) {
        bf16x8 v;
#pragma unroll
        for (int j = 0; j < 8; ++j) v[j] = (bf16_t)o[g * 8 + j];
        *(bf16x8*)(dst + g * 8) = v;
    }
}

// ------------------------------------------------------------------
// bf16 MFMA GEMM: 64x128 tile, BK=32, 4 waves (32x64 each), single-
// buffered 12KB LDS, 2-barrier loop — the empirically-best structure.
// MODE 0: A = nh fp32 [.,256] | skipb bf16 [.,32]; K=288; out KVb ldc256
// MODE 1: A = ph fp32 [.,128] | grep fp32 [.,256]; K=384; out Qb bf16
// MODE 2: A bf16 stride K; fp32 out ldc=512 (GRU rz|in|hn)
// MODE 3: bf16 out + relu    MODE 4: fp32 out = acc+bias+resid, row<Mlimit
// ------------------------------------------------------------------
template <int MODE>
__global__ __launch_bounds__(256) void mfma_gemm(
    const void* __restrict__ A0, const void* __restrict__ A1,
    const bf16_t* __restrict__ BT, const float* __restrict__ bias,
    void* __restrict__ out0v, const float* __restrict__ resid,
    int K, int Mlimit, int Nrows)
{
    __shared__ short AsS[64 * 32];   // [row][k] bf16, 64B rows
    __shared__ short BsS[128 * 32];  // [col][k]
    int tid = threadIdx.x;
    int lane = tid & 63, w = tid >> 6;
    int la = lane & 15, hi = lane >> 4;
    int m0 = (w & 1) * 32, n0 = (w >> 1) * 64;
    int row0 = blockIdx.y * 64, col0 = blockIdx.x * 128;

    f32x4 zero4 = {0.f, 0.f, 0.f, 0.f};
    f32x4 acc[2][4];
#pragma unroll
    for (int i = 0; i < 2; ++i)
#pragma unroll
        for (int j = 0; j < 4; ++j) acc[i][j] = zero4;

    const int ra = tid >> 2, ka = (tid & 3) * 8;   // A: 1 chunk (16B) / thread
    const int c1 = tid + 256;                       // B: 2 chunks / thread
    const int rb0 = tid >> 2, kb0 = (tid & 3) * 8;
    const int rb1 = c1 >> 2,  kb1 = (c1 & 3) * 8;

    for (int kt = 0; kt < K; kt += 32) {
        int gmA = row0 + ra;
        if (MODE == 0) {
            if (kt < 256) {  // kt uniform -> no divergence
                bf16x8 v = {};
                if (gmA < Nrows) {
                    const float* s = (const float*)A0 + (size_t)gmA * 256 + kt + ka;
                    v = cvt8(*(const float4*)s, *(const float4*)(s + 4));
                }
                *(bf16x8*)(AsS + (size_t)tid * 8) = v;
            } else {
                gload_lds16((const bf16_t*)A1 + (size_t)gmA * 32 + (kt - 256) + ka,
                            AsS + (size_t)tid * 8);
            }
        } else if (MODE == 1) {
            int gk = kt + ka;
            bf16x8 v = {};
            if (gmA < Nrows) {
                const float* s = (gk < 128) ? ((const float*)A0 + (size_t)gmA * 128 + gk)
                                            : ((const float*)A1 + (size_t)gmA * 256 + (gk - 128));
                v = cvt8(*(const float4*)s, *(const float4*)(s + 4));
            }
            *(bf16x8*)(AsS + (size_t)tid * 8) = v;
        } else {
            gload_lds16((const bf16_t*)A0 + (size_t)gmA * K + kt + ka,
                        AsS + (size_t)tid * 8);
        }
        gload_lds16(BT + (size_t)(col0 + rb0) * K + kt + kb0, BsS + (size_t)tid * 8);
        gload_lds16(BT + (size_t)(col0 + rb1) * K + kt + kb1, BsS + (size_t)c1 * 8);
        __syncthreads();
        bf16x8 a[2], b[4];
#pragma unroll
        for (int i = 0; i < 2; ++i)
            a[i] = *(const bf16x8*)(AsS + (m0 + i * 16 + la) * 32 + hi * 8);
#pragma unroll
        for (int j = 0; j < 4; ++j)
            b[j] = *(const bf16x8*)(BsS + (n0 + j * 16 + la) * 32 + hi * 8);
#pragma unroll
        for (int i = 0; i < 2; ++i)
#pragma unroll
            for (int j = 0; j < 4; ++j)
                acc[i][j] = __builtin_amdgcn_mfma_f32_16x16x32_bf16(a[i], b[j], acc[i][j], 0, 0, 0);
        __syncthreads();
    }

#pragma unroll
    for (int i = 0; i < 2; ++i) {
#pragma unroll
        for (int j = 0; j < 4; ++j) {
            int col = col0 + n0 + j * 16 + la;
            float bb = bias[col];
#pragma unroll
            for (int r = 0; r < 4; ++r) {
                int row = row0 + m0 + i * 16 + hi * 4 + r;
                float v = acc[i][j][r] + bb;
                if (MODE == 0) {
                    ((bf16_t*)out0v)[(size_t)row * 256 + col] = (bf16_t)v;  // KVb interleaved
                } else if (MODE == 1) {
                    ((bf16_t*)out0v)[(size_t)row * 128 + col] = (bf16_t)v;
                } else if (MODE == 2) {
                    ((float*)out0v)[(size_t)row * 512 + col] = v;
                } else if (MODE == 3) {
                    ((bf16_t*)out0v)[(size_t)row * 128 + col] = (bf16_t)fmaxf(v, 0.f);
                } else {  // MODE 4
                    if (row < Mlimit)
                        ((float*)out0v)[(size_t)row * 128 + col] = v + resid[(size_t)row * 128 + col];
                }
            }
        }
    }
}

// ------------------------------------------------------------------
// CSR build (cnt zeroed by prep_all)
// ------------------------------------------------------------------
__global__ void hist_kernel(const int* __restrict__ dst, int* __restrict__ cnt, int E_)
{
    int i = blockIdx.x * THREADS + threadIdx.x;
    if (i < E_) atomicAdd(&cnt[dst[i]], 1);
}

__global__ void scan_kernel(const int* __restrict__ cnt, int* __restrict__ offb, int P_)
{
    __shared__ int wsum[16];
    int tid = threadIdx.x;
    int lane = tid & 63, w = tid >> 6;
    int base = tid * 10;
    int c[10];
    int s = 0;
#pragma unroll
    for (int j = 0; j < 10; ++j) {
        int i = base + j;
        c[j] = (i < P_) ? cnt[i] : 0;
        s += c[j];
    }
    int pre = s;
    for (int o = 1; o < 64; o <<= 1) {
        int t = __shfl_up(pre, o);
        if (lane >= o) pre += t;
    }
    if (lane == 63) wsum[w] = pre;
    __syncthreads();
    if (w == 0 && lane < 16) {
        int v = wsum[lane];
        for (int o = 1; o < 16; o <<= 1) {
            int t = __shfl_up(v, o, 16);
            if (lane >= o) v += t;
        }
        wsum[lane] = v;
    }
    __syncthreads();
    int waveoff = (w == 0) ? 0 : wsum[w - 1];
    int run = waveoff + pre - s;
#pragma unroll
    for (int j = 0; j < 10; ++j) {
        int i = base + j;
        if (i <= P_) offb[i] = run;
        run += c[j];
    }
}

__global__ void fill_src_kernel(const int* __restrict__ dst, const int* __restrict__ src,
                                const int* __restrict__ offb, int* __restrict__ cur,
                                int* __restrict__ csrc, int E_)
{
    int i = blockIdx.x * THREADS + threadIdx.x;
    if (i < E_) {
        int d = dst[i];
        int pos = atomicAdd(&cur[d], 1);
        csrc[offb[d] + pos] = src[i];
    }
}

// ------------------------------------------------------------------
// fused attention + gather + rms/sigmoid gate (unchanged, proven)
// ------------------------------------------------------------------
__global__ __launch_bounds__(256) void edge_kernel(
    const int* __restrict__ offb, const int* __restrict__ csrc,
    const bf16_t* __restrict__ KVb, const bf16_t* __restrict__ Qb,
    const float* __restrict__ ph, const float* __restrict__ rms_w,
    const float* __restrict__ lin_w, bf16_t* __restrict__ AG, int P_)
{
    int tid = threadIdx.x;
    int p = blockIdx.x * 4 + (tid >> 6);
    if (p >= P_) return;
    int lane = tid & 63;
    int c = lane & 15, g = lane >> 4;

    bf16x8 q8 = *(const bf16x8*)(Qb + (size_t)p * 128 + c * 8);
    float qf[8];
#pragma unroll
    for (int j = 0; j < 8; ++j) qf[j] = (float)q8[j];

    int s0 = offb[p], e0 = offb[p + 1];
    float acc[8] = {};

    int i = s0 + g;
    for (; i + 12 < e0; i += 16) {
        int n0 = csrc[i], n1 = csrc[i + 4], n2 = csrc[i + 8], n3 = csrc[i + 12];
        const bf16_t* b0 = KVb + (size_t)n0 * 256 + c * 8;
        const bf16_t* b1 = KVb + (size_t)n1 * 256 + c * 8;
        const bf16_t* b2 = KVb + (size_t)n2 * 256 + c * 8;
        const bf16_t* b3 = KVb + (size_t)n3 * 256 + c * 8;
        bf16x8 k0 = *(const bf16x8*)b0, v0 = *(const bf16x8*)(b0 + 128);
        bf16x8 k1 = *(const bf16x8*)b1, v1 = *(const bf16x8*)(b1 + 128);
        bf16x8 k2 = *(const bf16x8*)b2, v2 = *(const bf16x8*)(b2 + 128);
        bf16x8 k3 = *(const bf16x8*)b3, v3 = *(const bf16x8*)(b3 + 128);
        float d0 = 0.f, d1 = 0.f, d2 = 0.f, d3 = 0.f;
#pragma unroll
        for (int j = 0; j < 8; ++j) {
            d0 += qf[j] * (float)k0[j]; d1 += qf[j] * (float)k1[j];
            d2 += qf[j] * (float)k2[j]; d3 += qf[j] * (float)k3[j];
        }
        d0 += __shfl_xor(d0, 1); d1 += __shfl_xor(d1, 1); d2 += __shfl_xor(d2, 1); d3 += __shfl_xor(d3, 1);
        d0 += __shfl_xor(d0, 2); d1 += __shfl_xor(d1, 2); d2 += __shfl_xor(d2, 2); d3 += __shfl_xor(d3, 2);
        d0 += __shfl_xor(d0, 4); d1 += __shfl_xor(d1, 4); d2 += __shfl_xor(d2, 4); d3 += __shfl_xor(d3, 4);
        d0 += __shfl_xor(d0, 8); d1 += __shfl_xor(d1, 8); d2 += __shfl_xor(d2, 8); d3 += __shfl_xor(d3, 8);
        float a0 = fmaxf(d0 * 0.1f, 0.f), a1 = fmaxf(d1 * 0.1f, 0.f);
        float a2 = fmaxf(d2 * 0.1f, 0.f), a3 = fmaxf(d3 * 0.1f, 0.f);
#pragma unroll
        for (int j = 0; j < 8; ++j)
            acc[j] += a0 * (float)v0[j] + a1 * (float)v1[j]
                    + a2 * (float)v2[j] + a3 * (float)v3[j];
    }
    for (; i < e0; i += 4) {
        int nA = csrc[i];
        const bf16_t* bA = KVb + (size_t)nA * 256 + c * 8;
        bf16x8 kA = *(const bf16x8*)bA;
        bf16x8 vA = *(const bf16x8*)(bA + 128);
        float dA = 0.f;
#pragma unroll
        for (int j = 0; j < 8; ++j) dA += qf[j] * (float)kA[j];
        dA += __shfl_xor(dA, 1);
        dA += __shfl_xor(dA, 2);
        dA += __shfl_xor(dA, 4);
        dA += __shfl_xor(dA, 8);
        float aA = fmaxf(dA * 0.1f, 0.f);
#pragma unroll
        for (int j = 0; j < 8; ++j) acc[j] += aA * (float)vA[j];
    }

    // reduce across the 4 edge-groups; afterwards every lane holds totals
#pragma unroll
    for (int j = 0; j < 8; ++j) {
        acc[j] += __shfl_xor(acc[j], 16);
        acc[j] += __shfl_xor(acc[j], 32);
    }

    // fused rms-norm * sigmoid gate
    float ss = 0.f;
#pragma unroll
    for (int j = 0; j < 8; ++j) ss += acc[j] * acc[j];
    ss += __shfl_xor(ss, 1); ss += __shfl_xor(ss, 2); ss += __shfl_xor(ss, 4); ss += __shfl_xor(ss, 8);
    float scale = rsqrtf(ss * (1.f / 128.f) + 1e-6f);
    if (g == 0) {
        int cb = c * 8;
        const float* hp = ph + (size_t)p * 128 + cb;
        float4 ha = *(const float4*)hp, hb = *(const float4*)(hp + 4);
        float hv[8] = {ha.x, ha.y, ha.z, ha.w, hb.x, hb.y, hb.z, hb.w};
        bf16x8 gv, hvb;
#pragma unroll
        for (int j = 0; j < 8; ++j) {
            float wsv = acc[j];
            float rv = wsv * scale * rms_w[cb + j];
            gv[j] = (bf16_t)(rv * sigmoidf_(wsv * lin_w[cb + j]));
            hvb[j] = (bf16_t)hv[j];
        }
        *(bf16x8*)(AG + (size_t)p * 256 + cb) = gv;
        *(bf16x8*)(AG + (size_t)p * 256 + 128 + cb) = hvb;
    }
}

// ------------------------------------------------------------------
// gru+ln pointwise: read G512 [Mq,512] fp32 (rz|zz folded, in, hn),
// h=ph fp32; compute h_new, LayerNorm -> LNb bf16 [Mq,128]
// ------------------------------------------------------------------
__global__ void gru_ln_kernel(const float* __restrict__ G512, const float* __restrict__ ph,
                              const float* __restrict__ ln_g, const float* __restrict__ ln_b,
                              bf16_t* __restrict__ LNb, int P_, int Mq)
{
    int tid = threadIdx.x;
    int g = tid >> 4, s = tid & 15;
    int p = blockIdx.x * 16 + g;
    if (p >= Mq) return;
    int cb = s * 8;
    if (p >= P_) {
        bf16x8 z = {};
        *(bf16x8*)(LNb + (size_t)p * 128 + cb) = z;
        return;
    }
    const float* G = G512 + (size_t)p * 512;
    float rz[8], zz[8], in_[8], hn_[8], hv[8];
#pragma unroll
    for (int q = 0; q < 2; ++q) {
        float4 v;
        v = *(const float4*)(G + cb + q * 4);        rz[q*4]=v.x; rz[q*4+1]=v.y; rz[q*4+2]=v.z; rz[q*4+3]=v.w;
        v = *(const float4*)(G + 128 + cb + q * 4);  zz[q*4]=v.x; zz[q*4+1]=v.y; zz[q*4+2]=v.z; zz[q*4+3]=v.w;
        v = *(const float4*)(G + 256 + cb + q * 4);  in_[q*4]=v.x; in_[q*4+1]=v.y; in_[q*4+2]=v.z; in_[q*4+3]=v.w;
        v = *(const float4*)(G + 384 + cb + q * 4);  hn_[q*4]=v.x; hn_[q*4+1]=v.y; hn_[q*4+2]=v.z; hn_[q*4+3]=v.w;
        v = *(const float4*)(ph + (size_t)p * 128 + cb + q * 4);
        hv[q*4]=v.x; hv[q*4+1]=v.y; hv[q*4+2]=v.z; hv[q*4+3]=v.w;
    }
    float hn[8];
    float sm = 0.f, sq = 0.f;
#pragma unroll
    for (int j = 0; j < 8; ++j) {
        float r = sigmoidf_(rz[j]);
        float z = sigmoidf_(zz[j]);
        float n = tanhf(in_[j] + r * hn_[j]);
        hn[j] = (1.f - z) * n + z * hv[j];
        sm += hn[j]; sq += hn[j] * hn[j];
    }
    sm += __shfl_xor(sm, 1); sm += __shfl_xor(sm, 2); sm += __shfl_xor(sm, 4); sm += __shfl_xor(sm, 8);
    sq += __shfl_xor(sq, 1); sq += __shfl_xor(sq, 2); sq += __shfl_xor(sq, 4); sq += __shfl_xor(sq, 8);
    float mu = sm * (1.f / 128.f);
    float var = sq * (1.f / 128.f) - mu * mu;
    float iv = rsqrtf(var + 1e-5f);
    bf16x8 o;
#pragma unroll
    for (int j = 0; j < 8; ++j) {
        int c = cb + j;
        o[j] = (bf16_t)((hn[j] - mu) * iv * ln_g[c] + ln_b[c]);
    }
    *(bf16x8*)(LNb + (size_t)p * 128 + cb) = o;
}

// ------------------------------------------------------------------
extern "C" void kernel_launch(void* const* d_in, const int* in_sizes, int n_in,
                              void* d_out, int out_size, void* d_ws, size_t ws_size,
                              hipStream_t stream)
{
    const float* nh      = (const float*)d_in[0];
    const float* energy  = (const float*)d_in[1];
    const float* eta     = (const float*)d_in[2];
    const float* phi     = (const float*)d_in[3];
    const float* layer   = (const float*)d_in[4];
    const float* eta_l   = (const float*)d_in[5];
    const float* phi_l   = (const float*)d_in[6];
    const float* ene_l   = (const float*)d_in[7];
    const float* track   = (const float*)d_in[8];
    const float* ph      = (const float*)d_in[9];
    const float* grep    = (const float*)d_in[10];
    const int*   esrc    = (const int*)d_in[11];
    const int*   edst    = (const int*)d_in[12];
    const float* W_key   = (const float*)d_in[13];
    const float* b_key   = (const float*)d_in[14];
    const float* W_val   = (const float*)d_in[15];
    const float* b_val   = (const float*)d_in[16];
    const float* W_q     = (const float*)d_in[17];
    const float* b_q     = (const float*)d_in[18];
    const float* W_ih    = (const float*)d_in[19];
    const float* b_ih    = (const float*)d_in[20];
    const float* W_hh    = (const float*)d_in[21];
    const float* b_hh    = (const float*)d_in[22];
    const float* ln_g    = (const float*)d_in[23];
    const float* ln_b    = (const float*)d_in[24];
    const float* W1      = (const float*)d_in[25];
    const float* b1      = (const float*)d_in[26];
    const float* W2      = (const float*)d_in[27];
    const float* b2      = (const float*)d_in[28];
    const float* rms_w   = (const float*)d_in[29];
    const float* lin_w   = (const float*)d_in[30];

    const int N = in_sizes[1];
    const int P = in_sizes[9] / 128;
    const int E = in_sizes[11];
    const int Mpad = ((N + 127) / 128) * 128;   // 100096
    const int Mq   = ((P + 127) / 128) * 128;   // 10112

    // workspace layout (byte offsets, 256B aligned)
    char* base = (char*)d_ws;
    size_t off = 0;
    auto alloc = [&](size_t bytes) { void* p = base + off; off = (off + bytes + 255) & ~(size_t)255; return p; };
    bf16_t* skipb = (bf16_t*)alloc((size_t)Mpad * 32 * 2);
    bf16_t* WbfT  = (bf16_t*)alloc(256 * 288 * 2);
    bf16_t* WqT   = (bf16_t*)alloc(128 * 384 * 2);
    float*  bpn   = (float*)alloc(256 * 4);
    float*  bpq   = (float*)alloc(128 * 4);
    bf16_t* KVb   = (bf16_t*)alloc((size_t)Mpad * 256 * 2);
    bf16_t* Qb    = (bf16_t*)alloc((size_t)Mq * 128 * 2);
    // cnt and cur MUST be contiguous: prep_all zeroes cnt[0..2P)
    int*    cnt   = (int*)alloc((size_t)(2 * P) * 4);
    int*    cur   = cnt + P;
    int*    offb  = (int*)alloc((size_t)(P + 1) * 4);
    int*    csrc  = (int*)alloc((size_t)E * 4);
    bf16_t* AG    = (bf16_t*)alloc((size_t)Mq * 256 * 2);
    bf16_t* BTg   = (bf16_t*)alloc(512 * 256 * 2);
    bf16_t* W1Tp  = (bf16_t*)alloc(128 * 128 * 2);
    bf16_t* W2Tp  = (bf16_t*)alloc(128 * 128 * 2);
    float*  bgru  = (float*)alloc(512 * 4);
    float*  b1p   = (float*)alloc(128 * 4);
    float*  G512  = (float*)alloc((size_t)Mq * 512 * 4);
    bf16_t* LNb   = (bf16_t*)alloc((size_t)Mq * 128 * 2);
    bf16_t* M1    = (bf16_t*)alloc((size_t)Mq * 128 * 2);

    // 1. merged weight prep (+ cnt zero + AG pad zero) + skip features
    {
        int padElems = (Mq - P) * 256;
        int T1 = 256 * 288 + 128 * 384 + 256 + 128;
        int T2 = 512 * 256 + 128 * 128 + 128 * 128 + 512 + 128 + 2 * P + padElems;
        prep_all<<<(T1 + T2 + THREADS - 1) / THREADS, THREADS, 0, stream>>>(
            W_key, W_val, W_q, b_key, b_val, b_q, WbfT, WqT, bpn, bpq,
            W_ih, W_hh, b_ih, b_hh, W1, b1, W2, BTg, W1Tp, W2Tp, bgru, b1p,
            cnt, 2 * P, AG, P, padElems);
        skip_kernel<<<(Mpad + THREADS - 1) / THREADS, THREADS, 0, stream>>>(
            energy, eta, phi, layer, eta_l, phi_l, ene_l, track, skipb, N, Mpad);
    }
    // 2. K/V GEMM (r8/r13 structure, measured best) + Q GEMM
    mfma_gemm<0><<<dim3(2, Mpad / 64), THREADS, 0, stream>>>(
        nh, skipb, WbfT, bpn, KVb, nullptr, 288, 0, N);
    mfma_gemm<1><<<dim3(1, Mq / 64), THREADS, 0, stream>>>(
        ph, grep, WqT, bpq, Qb, nullptr, 384, 0, P);
    // 3. CSR build (src ids stored directly)
    hist_kernel<<<(E + THREADS - 1) / THREADS, THREADS, 0, stream>>>(edst, cnt, E);
    scan_kernel<<<1, 1024, 0, stream>>>(cnt, offb, P);
    fill_src_kernel<<<(E + THREADS - 1) / THREADS, THREADS, 0, stream>>>(
        edst, esrc, offb, cur, csrc, E);
    // 4. fused attention + gather + gate -> AG
    edge_kernel<<<(P + 3) / 4, THREADS, 0, stream>>>(
        offb, csrc, KVb, Qb, ph, rms_w, lin_w, AG, P);
    // 5. node update: GRU GEMM (512 cols, r/z folded) -> pointwise+LN -> MLP
    mfma_gemm<2><<<dim3(4, Mq / 64), THREADS, 0, stream>>>(
        AG, nullptr, BTg, bgru, G512, nullptr, 256, 0, Mq);
    gru_ln_kernel<<<Mq / 16, THREADS, 0, stream>>>(G512, ph, ln_g, ln_b, LNb, P, Mq);
    mfma_gemm<3><<<dim3(1, Mq / 64), THREADS, 0, stream>>>(
        LNb, nullptr, W1Tp, b1p, M1, nullptr, 128, 0, Mq);
    mfma_gemm<4><<<dim3(1, Mq / 64), THREADS, 0, stream>>>(
        M1, nullptr, W2Tp, b2, d_out, ph, 128, P, Mq);
}

// Round 19
// 214.241 us; speedup vs baseline: 1.2188x; 1.0357x over previous
//
#include <hip/hip_runtime.h>
#include <hip/hip_bf16.h>
#include <math.h>

#define THREADS 256

typedef __bf16 bf16_t;
typedef __bf16 bf16x8 __attribute__((ext_vector_type(8)));
typedef float f32x4 __attribute__((ext_vector_type(4)));

__device__ __forceinline__ float sigmoidf_(float x) { return 1.f / (1.f + expf(-x)); }

__device__ __forceinline__ void gload_lds16(const void* g, void* l) {
    __builtin_amdgcn_global_load_lds((const __attribute__((address_space(1))) void*)g,
                                     (__attribute__((address_space(3))) void*)l, 16, 0, 0);
}

__device__ __forceinline__ bf16x8 cvt8(float4 a, float4 b) {
    bf16x8 v;
    v[0] = (bf16_t)a.x; v[1] = (bf16_t)a.y; v[2] = (bf16_t)a.z; v[3] = (bf16_t)a.w;
    v[4] = (bf16_t)b.x; v[5] = (bf16_t)b.y; v[6] = (bf16_t)b.z; v[7] = (bf16_t)b.w;
    return v;
}

// ------------------------------------------------------------------
// prep_all: merged weight prep (r18 config: r/z-folded BTg [512][256]).
// ------------------------------------------------------------------
__global__ void prep_all(const float* __restrict__ W_key, const float* __restrict__ W_val,
                         const float* __restrict__ W_q, const float* __restrict__ b_key,
                         const float* __restrict__ b_val, const float* __restrict__ b_q,
                         bf16_t* __restrict__ WbfT, bf16_t* __restrict__ WqT,
                         float* __restrict__ bpn, float* __restrict__ bpq,
                         const float* __restrict__ W_ih, const float* __restrict__ W_hh,
                         const float* __restrict__ b_ih, const float* __restrict__ b_hh,
                         const float* __restrict__ W1, const float* __restrict__ b1,
                         const float* __restrict__ W2,
                         bf16_t* __restrict__ BTg, bf16_t* __restrict__ W1Tp,
                         bf16_t* __restrict__ W2Tp, float* __restrict__ bgru,
                         float* __restrict__ b1p,
                         int* __restrict__ cnt, int twoP,
                         bf16_t* __restrict__ AG, int padStart, int padElems)
{
    int i0 = blockIdx.x * THREADS + threadIdx.x;
    const int NW = 256 * 288, NQ = 128 * 384;
    const int T1 = NW + NQ + 256 + 128;
    if (i0 < T1) {
        int i = i0;
        if (i < NW) {
            int c = i / 288, k = i - c * 288;
            float v = 0.f;
            if (k < 283) {
                if (c < 100) v = W_key[k * 100 + c];
                else if (c >= 128 && c < 256) v = W_val[k * 128 + (c - 128)];
            }
            WbfT[i] = (bf16_t)v;
        } else if (i < NW + NQ) {
            int j = i - NW;
            int c = j / 384, k = j - c * 384;
            WqT[j] = (bf16_t)((c < 100) ? W_q[k * 100 + c] : 0.f);
        } else if (i < NW + NQ + 256) {
            int c = i - NW - NQ;
            bpn[c] = (c < 100) ? b_key[c] : ((c >= 128 && c < 256) ? b_val[c - 128] : 0.f);
        } else {
            int c = i - NW - NQ - 256;
            bpq[c] = (c < 100) ? b_q[c] : 0.f;
        }
        return;
    }
    int i = i0 - T1;
    const int NG = 512 * 256, N1 = 128 * 128, N2 = 128 * 128;
    const int NB = NG + N1 + N2 + 512 + 128;
    if (i < NG) {
        int c = i >> 8, k = i & 255;   // col c of 512, k of 256 ([gated|h])
        float v = 0.f;
        if (c < 256) {
            v = (k < 128) ? W_ih[k * 384 + c] : W_hh[(k - 128) * 384 + c];  // fused r/z
        } else if (c < 384) {
            if (k < 128) v = W_ih[k * 384 + (c - 256) + 256];   // i_n
        } else {
            if (k >= 128) v = W_hh[(k - 128) * 384 + (c - 384) + 256];  // h_n
        }
        BTg[i] = (bf16_t)v;
    } else if (i < NG + N1) {
        int j = i - NG; int c = j >> 7, k = j & 127;
        W1Tp[j] = (bf16_t)((c < 64) ? W1[k * 64 + c] : 0.f);
    } else if (i < NG + N1 + N2) {
        int j = i - NG - N1; int c = j >> 7, k = j & 127;
        W2Tp[j] = (bf16_t)((k < 64) ? W2[k * 128 + c] : 0.f);
    } else if (i < NG + N1 + N2 + 512) {
        int c = i - NG - N1 - N2;
        float v;
        if (c < 256)      v = b_ih[c] + b_hh[c];
        else if (c < 384) v = b_ih[(c - 256) + 256];
        else              v = b_hh[(c - 384) + 256];
        bgru[c] = v;
    } else if (i < NB) {
        int c = i - NG - N1 - N2 - 512;
        b1p[c] = (c < 64) ? b1[c] : 0.f;
    } else if (i < NB + twoP) {
        cnt[i - NB] = 0;
    } else if (i < NB + twoP + padElems) {
        int j = i - NB - twoP;
        AG[(size_t)padStart * 256 + j] = (bf16_t)0.f;
    }
}

// skip features -> skipb bf16 [Mpad,32] (27 real + 5 zero; pad rows zero)
__global__ void skip_kernel(const float* __restrict__ energy, const float* __restrict__ eta,
                            const float* __restrict__ phi, const float* __restrict__ layer,
                            const float* __restrict__ eta_l, const float* __restrict__ phi_l,
                            const float* __restrict__ ene_l, const float* __restrict__ track,
                            bf16_t* __restrict__ skipb, int N_, int Mpad)
{
    int n = blockIdx.x * THREADS + threadIdx.x;
    if (n >= Mpad) return;
    float o[32];
#pragma unroll
    for (int j = 0; j < 32; ++j) o[j] = 0.f;
    if (n < N_) {
        o[0] = (logf(energy[n]) - 4.0f) * 0.5f;
        o[1] = eta[n] * (1.f / 1.5f);
        o[2] = phi[n];
        o[3] = layer[n];
#pragma unroll
        for (int j = 0; j < 6; ++j) o[4 + j]  = eta_l[n * 6 + j] * (1.f / 1.5f);
#pragma unroll
        for (int j = 0; j < 6; ++j) o[10 + j] = phi_l[n * 6 + j];
#pragma unroll
        for (int j = 0; j < 6; ++j) o[16 + j] = ene_l[n * 6 + j];
#pragma unroll
        for (int j = 0; j < 5; ++j) o[22 + j] = track[n * 5 + j];
    }
    bf16_t* dst = skipb + (size_t)n * 32;
#pragma unroll
    for (int g = 0; g < 4; ++g) {
        bf16x8 v;
#pragma unroll
        for (int j = 0; j < 8; ++j) v[j] = (bf16_t)o[g * 8 + j];
        *(bf16x8*)(dst + g * 8) = v;
    }
}

// ------------------------------------------------------------------
// kv_gemm512: BM=64 x BN=256, 512 threads = 8 waves (2x4), 20KB LDS,
// 2-barrier loop. Same wave budget as r8 (4 blk/CU x 8 waves = 32), but
// A is read ONCE (grid.x=2 -> 1 halves FETCH 107->54MB) and B staged
// once per 64 rows instead of twice.
// ------------------------------------------------------------------
__global__ __launch_bounds__(512) void kv_gemm512(
    const float* __restrict__ nh, const bf16_t* __restrict__ skipb,
    const bf16_t* __restrict__ BT, const float* __restrict__ bias,
    bf16_t* __restrict__ KVb, int N_)
{
    __shared__ short AsS[64 * 32];    // 4 KB
    __shared__ short BsS[256 * 32];   // 16 KB
    int tid = threadIdx.x;
    int lane = tid & 63, w = tid >> 6;          // 8 waves
    int la = lane & 15, hi = lane >> 4;
    int m0 = (w & 1) * 32, n0 = (w >> 1) * 64;  // 2x4 wave grid
    int row0 = blockIdx.x * 64;

    f32x4 zero4 = {0.f, 0.f, 0.f, 0.f};
    f32x4 acc[2][4];
#pragma unroll
    for (int i = 0; i < 2; ++i)
#pragma unroll
        for (int j = 0; j < 4; ++j) acc[i][j] = zero4;

    const int ra = tid >> 2, ka = (tid & 3) * 8;    // A: tid<256 stages 1 chunk
    const int cB1 = tid + 512;                       // B: 2 chunks / thread
    const int rb0 = tid >> 2, kb0 = (tid & 3) * 8;   // rows 0..127
    const int rb1 = cB1 >> 2, kb1 = (cB1 & 3) * 8;   // rows 128..255

    for (int kt = 0; kt < 288; kt += 32) {
        if (tid < 256) {  // wave-uniform predicate (waves 0-3)
            int gmA = row0 + ra;
            if (kt < 256) {
                bf16x8 v = {};
                if (gmA < N_) {
                    const float* s = nh + (size_t)gmA * 256 + kt + ka;
                    v = cvt8(*(const float4*)s, *(const float4*)(s + 4));
                }
                *(bf16x8*)(AsS + (size_t)tid * 8) = v;
            } else {
                gload_lds16(skipb + (size_t)gmA * 32 + (kt - 256) + ka,
                            AsS + (size_t)tid * 8);
            }
        }
        gload_lds16(BT + (size_t)rb0 * 288 + kt + kb0, BsS + (size_t)tid * 8);
        gload_lds16(BT + (size_t)rb1 * 288 + kt + kb1, BsS + (size_t)cB1 * 8);
        __syncthreads();
        bf16x8 a[2], b[4];
#pragma unroll
        for (int i = 0; i < 2; ++i)
            a[i] = *(const bf16x8*)(AsS + (m0 + i * 16 + la) * 32 + hi * 8);
#pragma unroll
        for (int j = 0; j < 4; ++j)
            b[j] = *(const bf16x8*)(BsS + (n0 + j * 16 + la) * 32 + hi * 8);
#pragma unroll
        for (int i = 0; i < 2; ++i)
#pragma unroll
            for (int j = 0; j < 4; ++j)
                acc[i][j] = __builtin_amdgcn_mfma_f32_16x16x32_bf16(a[i], b[j], acc[i][j], 0, 0, 0);
        __syncthreads();
    }

#pragma unroll
    for (int i = 0; i < 2; ++i) {
#pragma unroll
        for (int j = 0; j < 4; ++j) {
            int col = n0 + j * 16 + la;
            float bb = bias[col];
#pragma unroll
            for (int r = 0; r < 4; ++r) {
                int row = row0 + m0 + i * 16 + hi * 4 + r;
                KVb[(size_t)row * 256 + col] = (bf16_t)(acc[i][j][r] + bb);
            }
        }
    }
}

// ------------------------------------------------------------------
// bf16 MFMA GEMM (modes 1-4): 64x128 tile, BK=32, 4 waves, 12KB LDS.
// MODE 1: A = ph fp32 [.,128] | grep fp32 [.,256]; K=384; out Qb bf16
// MODE 2: A bf16 stride K; fp32 out ldc=512 (GRU rz|in|hn)
// MODE 3: bf16 out + relu    MODE 4: fp32 out = acc+bias+resid, row<Mlimit
// ------------------------------------------------------------------
template <int MODE>
__global__ __launch_bounds__(256) void mfma_gemm(
    const void* __restrict__ A0, const void* __restrict__ A1,
    const bf16_t* __restrict__ BT, const float* __restrict__ bias,
    void* __restrict__ out0v, const float* __restrict__ resid,
    int K, int Mlimit, int Nrows)
{
    __shared__ short AsS[64 * 32];
    __shared__ short BsS[128 * 32];
    int tid = threadIdx.x;
    int lane = tid & 63, w = tid >> 6;
    int la = lane & 15, hi = lane >> 4;
    int m0 = (w & 1) * 32, n0 = (w >> 1) * 64;
    int row0 = blockIdx.y * 64, col0 = blockIdx.x * 128;

    f32x4 zero4 = {0.f, 0.f, 0.f, 0.f};
    f32x4 acc[2][4];
#pragma unroll
    for (int i = 0; i < 2; ++i)
#pragma unroll
        for (int j = 0; j < 4; ++j) acc[i][j] = zero4;

    const int ra = tid >> 2, ka = (tid & 3) * 8;
    const int c1 = tid + 256;
    const int rb0 = tid >> 2, kb0 = (tid & 3) * 8;
    const int rb1 = c1 >> 2,  kb1 = (c1 & 3) * 8;

    for (int kt = 0; kt < K; kt += 32) {
        int gmA = row0 + ra;
        if (MODE == 1) {
            int gk = kt + ka;
            bf16x8 v = {};
            if (gmA < Nrows) {
                const float* s = (gk < 128) ? ((const float*)A0 + (size_t)gmA * 128 + gk)
                                            : ((const float*)A1 + (size_t)gmA * 256 + (gk - 128));
                v = cvt8(*(const float4*)s, *(const float4*)(s + 4));
            }
            *(bf16x8*)(AsS + (size_t)tid * 8) = v;
        } else {
            gload_lds16((const bf16_t*)A0 + (size_t)gmA * K + kt + ka,
                        AsS + (size_t)tid * 8);
        }
        gload_lds16(BT + (size_t)(col0 + rb0) * K + kt + kb0, BsS + (size_t)tid * 8);
        gload_lds16(BT + (size_t)(col0 + rb1) * K + kt + kb1, BsS + (size_t)c1 * 8);
        __syncthreads();
        bf16x8 a[2], b[4];
#pragma unroll
        for (int i = 0; i < 2; ++i)
            a[i] = *(const bf16x8*)(AsS + (m0 + i * 16 + la) * 32 + hi * 8);
#pragma unroll
        for (int j = 0; j < 4; ++j)
            b[j] = *(const bf16x8*)(BsS + (n0 + j * 16 + la) * 32 + hi * 8);
#pragma unroll
        for (int i = 0; i < 2; ++i)
#pragma unroll
            for (int j = 0; j < 4; ++j)
                acc[i][j] = __builtin_amdgcn_mfma_f32_16x16x32_bf16(a[i], b[j], acc[i][j], 0, 0, 0);
        __syncthreads();
    }

#pragma unroll
    for (int i = 0; i < 2; ++i) {
#pragma unroll
        for (int j = 0; j < 4; ++j) {
            int col = col0 + n0 + j * 16 + la;
            float bb = bias[col];
#pragma unroll
            for (int r = 0; r < 4; ++r) {
                int row = row0 + m0 + i * 16 + hi * 4 + r;
                float v = acc[i][j][r] + bb;
                if (MODE == 1) {
                    ((bf16_t*)out0v)[(size_t)row * 128 + col] = (bf16_t)v;
                } else if (MODE == 2) {
                    ((float*)out0v)[(size_t)row * 512 + col] = v;
                } else if (MODE == 3) {
                    ((bf16_t*)out0v)[(size_t)row * 128 + col] = (bf16_t)fmaxf(v, 0.f);
                } else {  // MODE 4
                    if (row < Mlimit)
                        ((float*)out0v)[(size_t)row * 128 + col] = v + resid[(size_t)row * 128 + col];
                }
            }
        }
    }
}

// ------------------------------------------------------------------
// CSR build (cnt zeroed by prep_all)
// ------------------------------------------------------------------
__global__ void hist_kernel(const int* __restrict__ dst, int* __restrict__ cnt, int E_)
{
    int i = blockIdx.x * THREADS + threadIdx.x;
    if (i < E_) atomicAdd(&cnt[dst[i]], 1);
}

__global__ void scan_kernel(const int* __restrict__ cnt, int* __restrict__ offb, int P_)
{
    __shared__ int wsum[16];
    int tid = threadIdx.x;
    int lane = tid & 63, w = tid >> 6;
    int base = tid * 10;
    int c[10];
    int s = 0;
#pragma unroll
    for (int j = 0; j < 10; ++j) {
        int i = base + j;
        c[j] = (i < P_) ? cnt[i] : 0;
        s += c[j];
    }
    int pre = s;
    for (int o = 1; o < 64; o <<= 1) {
        int t = __shfl_up(pre, o);
        if (lane >= o) pre += t;
    }
    if (lane == 63) wsum[w] = pre;
    __syncthreads();
    if (w == 0 && lane < 16) {
        int v = wsum[lane];
        for (int o = 1; o < 16; o <<= 1) {
            int t = __shfl_up(v, o, 16);
            if (lane >= o) v += t;
        }
        wsum[lane] = v;
    }
    __syncthreads();
    int waveoff = (w == 0) ? 0 : wsum[w - 1];
    int run = waveoff + pre - s;
#pragma unroll
    for (int j = 0; j < 10; ++j) {
        int i = base + j;
        if (i <= P_) offb[i] = run;
        run += c[j];
    }
}

__global__ void fill_src_kernel(const int* __restrict__ dst, const int* __restrict__ src,
                                const int* __restrict__ offb, int* __restrict__ cur,
                                int* __restrict__ csrc, int E_)
{
    int i = blockIdx.x * THREADS + threadIdx.x;
    if (i < E_) {
        int d = dst[i];
        int pos = atomicAdd(&cur[d], 1);
        csrc[offb[d] + pos] = src[i];
    }
}

// ------------------------------------------------------------------
// fused attention + gather + rms/sigmoid gate (unchanged, proven)
// ------------------------------------------------------------------
__global__ __launch_bounds__(256) void edge_kernel(
    const int* __restrict__ offb, const int* __restrict__ csrc,
    const bf16_t* __restrict__ KVb, const bf16_t* __restrict__ Qb,
    const float* __restrict__ ph, const float* __restrict__ rms_w,
    const float* __restrict__ lin_w, bf16_t* __restrict__ AG, int P_)
{
    int tid = threadIdx.x;
    int p = blockIdx.x * 4 + (tid >> 6);
    if (p >= P_) return;
    int lane = tid & 63;
    int c = lane & 15, g = lane >> 4;

    bf16x8 q8 = *(const bf16x8*)(Qb + (size_t)p * 128 + c * 8);
    float qf[8];
#pragma unroll
    for (int j = 0; j < 8; ++j) qf[j] = (float)q8[j];

    int s0 = offb[p], e0 = offb[p + 1];
    float acc[8] = {};

    int i = s0 + g;
    for (; i + 12 < e0; i += 16) {
        int n0 = csrc[i], n1 = csrc[i + 4], n2 = csrc[i + 8], n3 = csrc[i + 12];
        const bf16_t* b0 = KVb + (size_t)n0 * 256 + c * 8;
        const bf16_t* b1 = KVb + (size_t)n1 * 256 + c * 8;
        const bf16_t* b2 = KVb + (size_t)n2 * 256 + c * 8;
        const bf16_t* b3 = KVb + (size_t)n3 * 256 + c * 8;
        bf16x8 k0 = *(const bf16x8*)b0, v0 = *(const bf16x8*)(b0 + 128);
        bf16x8 k1 = *(const bf16x8*)b1, v1 = *(const bf16x8*)(b1 + 128);
        bf16x8 k2 = *(const bf16x8*)b2, v2 = *(const bf16x8*)(b2 + 128);
        bf16x8 k3 = *(const bf16x8*)b3, v3 = *(const bf16x8*)(b3 + 128);
        float d0 = 0.f, d1 = 0.f, d2 = 0.f, d3 = 0.f;
#pragma unroll
        for (int j = 0; j < 8; ++j) {
            d0 += qf[j] * (float)k0[j]; d1 += qf[j] * (float)k1[j];
            d2 += qf[j] * (float)k2[j]; d3 += qf[j] * (float)k3[j];
        }
        d0 += __shfl_xor(d0, 1); d1 += __shfl_xor(d1, 1); d2 += __shfl_xor(d2, 1); d3 += __shfl_xor(d3, 1);
        d0 += __shfl_xor(d0, 2); d1 += __shfl_xor(d1, 2); d2 += __shfl_xor(d2, 2); d3 += __shfl_xor(d3, 2);
        d0 += __shfl_xor(d0, 4); d1 += __shfl_xor(d1, 4); d2 += __shfl_xor(d2, 4); d3 += __shfl_xor(d3, 4);
        d0 += __shfl_xor(d0, 8); d1 += __shfl_xor(d1, 8); d2 += __shfl_xor(d2, 8); d3 += __shfl_xor(d3, 8);
        float a0 = fmaxf(d0 * 0.1f, 0.f), a1 = fmaxf(d1 * 0.1f, 0.f);
        float a2 = fmaxf(d2 * 0.1f, 0.f), a3 = fmaxf(d3 * 0.1f, 0.f);
#pragma unroll
        for (int j = 0; j < 8; ++j)
            acc[j] += a0 * (float)v0[j] + a1 * (float)v1[j]
                    + a2 * (float)v2[j] + a3 * (float)v3[j];
    }
    for (; i < e0; i += 4) {
        int nA = csrc[i];
        const bf16_t* bA = KVb + (size_t)nA * 256 + c * 8;
        bf16x8 kA = *(const bf16x8*)bA;
        bf16x8 vA = *(const bf16x8*)(bA + 128);
        float dA = 0.f;
#pragma unroll
        for (int j = 0; j < 8; ++j) dA += qf[j] * (float)kA[j];
        dA += __shfl_xor(dA, 1);
        dA += __shfl_xor(dA, 2);
        dA += __shfl_xor(dA, 4);
        dA += __shfl_xor(dA, 8);
        float aA = fmaxf(dA * 0.1f, 0.f);
#pragma unroll
        for (int j = 0; j < 8; ++j) acc[j] += aA * (float)vA[j];
    }

    // reduce across the 4 edge-groups; afterwards every lane holds totals
#pragma unroll
    for (int j = 0; j < 8; ++j) {
        acc[j] += __shfl_xor(acc[j], 16);
        acc[j] += __shfl_xor(acc[j], 32);
    }

    // fused rms-norm * sigmoid gate
    float ss = 0.f;
#pragma unroll
    for (int j = 0; j < 8; ++j) ss += acc[j] * acc[j];
    ss += __shfl_xor(ss, 1); ss += __shfl_xor(ss, 2); ss += __shfl_xor(ss, 4); ss += __shfl_xor(ss, 8);
    float scale = rsqrtf(ss * (1.f / 128.f) + 1e-6f);
    if (g == 0) {
        int cb = c * 8;
        const float* hp = ph + (size_t)p * 128 + cb;
        float4 ha = *(const float4*)hp, hb = *(const float4*)(hp + 4);
        float hv[8] = {ha.x, ha.y, ha.z, ha.w, hb.x, hb.y, hb.z, hb.w};
        bf16x8 gv, hvb;
#pragma unroll
        for (int j = 0; j < 8; ++j) {
            float wsv = acc[j];
            float rv = wsv * scale * rms_w[cb + j];
            gv[j] = (bf16_t)(rv * sigmoidf_(wsv * lin_w[cb + j]));
            hvb[j] = (bf16_t)hv[j];
        }
        *(bf16x8*)(AG + (size_t)p * 256 + cb) = gv;
        *(bf16x8*)(AG + (size_t)p * 256 + 128 + cb) = hvb;
    }
}

// ------------------------------------------------------------------
// gru+ln pointwise: read G512 [Mq,512] fp32 (rz folded | in | hn),
// h=ph fp32; compute h_new, LayerNorm -> LNb bf16 [Mq,128]
// ------------------------------------------------------------------
__global__ void gru_ln_kernel(const float* __restrict__ G512, const float* __restrict__ ph,
                              const float* __restrict__ ln_g, const float* __restrict__ ln_b,
                              bf16_t* __restrict__ LNb, int P_, int Mq)
{
    int tid = threadIdx.x;
    int g = tid >> 4, s = tid & 15;
    int p = blockIdx.x * 16 + g;
    if (p >= Mq) return;
    int cb = s * 8;
    if (p >= P_) {
        bf16x8 z = {};
        *(bf16x8*)(LNb + (size_t)p * 128 + cb) = z;
        return;
    }
    const float* G = G512 + (size_t)p * 512;
    float rz[8], zz[8], in_[8], hn_[8], hv[8];
#pragma unroll
    for (int q = 0; q < 2; ++q) {
        float4 v;
        v = *(const float4*)(G + cb + q * 4);        rz[q*4]=v.x; rz[q*4+1]=v.y; rz[q*4+2]=v.z; rz[q*4+3]=v.w;
        v = *(const float4*)(G + 128 + cb + q * 4);  zz[q*4]=v.x; zz[q*4+1]=v.y; zz[q*4+2]=v.z; zz[q*4+3]=v.w;
        v = *(const float4*)(G + 256 + cb + q * 4);  in_[q*4]=v.x; in_[q*4+1]=v.y; in_[q*4+2]=v.z; in_[q*4+3]=v.w;
        v = *(const float4*)(G + 384 + cb + q * 4);  hn_[q*4]=v.x; hn_[q*4+1]=v.y; hn_[q*4+2]=v.z; hn_[q*4+3]=v.w;
        v = *(const float4*)(ph + (size_t)p * 128 + cb + q * 4);
        hv[q*4]=v.x; hv[q*4+1]=v.y; hv[q*4+2]=v.z; hv[q*4+3]=v.w;
    }
    float hn[8];
    float sm = 0.f, sq = 0.f;
#pragma unroll
    for (int j = 0; j < 8; ++j) {
        float r = sigmoidf_(rz[j]);
        float z = sigmoidf_(zz[j]);
        float n = tanhf(in_[j] + r * hn_[j]);
        hn[j] = (1.f - z) * n + z * hv[j];
        sm += hn[j]; sq += hn[j] * hn[j];
    }
    sm += __shfl_xor(sm, 1); sm += __shfl_xor(sm, 2); sm += __shfl_xor(sm, 4); sm += __shfl_xor(sm, 8);
    sq += __shfl_xor(sq, 1); sq += __shfl_xor(sq, 2); sq += __shfl_xor(sq, 4); sq += __shfl_xor(sq, 8);
    float mu = sm * (1.f / 128.f);
    float var = sq * (1.f / 128.f) - mu * mu;
    float iv = rsqrtf(var + 1e-5f);
    bf16x8 o;
#pragma unroll
    for (int j = 0; j < 8; ++j) {
        int c = cb + j;
        o[j] = (bf16_t)((hn[j] - mu) * iv * ln_g[c] + ln_b[c]);
    }
    *(bf16x8*)(LNb + (size_t)p * 128 + cb) = o;
}

// ------------------------------------------------------------------
extern "C" void kernel_launch(void* const* d_in, const int* in_sizes, int n_in,
                              void* d_out, int out_size, void* d_ws, size_t ws_size,
                              hipStream_t stream)
{
    const float* nh      = (const float*)d_in[0];
    const float* energy  = (const float*)d_in[1];
    const float* eta     = (const float*)d_in[2];
    const float* phi     = (const float*)d_in[3];
    const float* layer   = (const float*)d_in[4];
    const float* eta_l   = (const float*)d_in[5];
    const float* phi_l   = (const float*)d_in[6];
    const float* ene_l   = (const float*)d_in[7];
    const float* track   = (const float*)d_in[8];
    const float* ph      = (const float*)d_in[9];
    const float* grep    = (const float*)d_in[10];
    const int*   esrc    = (const int*)d_in[11];
    const int*   edst    = (const int*)d_in[12];
    const float* W_key   = (const float*)d_in[13];
    const float* b_key   = (const float*)d_in[14];
    const float* W_val   = (const float*)d_in[15];
    const float* b_val   = (const float*)d_in[16];
    const float* W_q     = (const float*)d_in[17];
    const float* b_q     = (const float*)d_in[18];
    const float* W_ih    = (const float*)d_in[19];
    const float* b_ih    = (const float*)d_in[20];
    const float* W_hh    = (const float*)d_in[21];
    const float* b_hh    = (const float*)d_in[22];
    const float* ln_g    = (const float*)d_in[23];
    const float* ln_b    = (const float*)d_in[24];
    const float* W1      = (const float*)d_in[25];
    const float* b1      = (const float*)d_in[26];
    const float* W2      = (const float*)d_in[27];
    const float* b2      = (const float*)d_in[28];
    const float* rms_w   = (const float*)d_in[29];
    const float* lin_w   = (const float*)d_in[30];

    const int N = in_sizes[1];
    const int P = in_sizes[9] / 128;
    const int E = in_sizes[11];
    const int Mpad = ((N + 127) / 128) * 128;   // 100096
    const int Mq   = ((P + 127) / 128) * 128;   // 10112

    // workspace layout (byte offsets, 256B aligned)
    char* base = (char*)d_ws;
    size_t off = 0;
    auto alloc = [&](size_t bytes) { void* p = base + off; off = (off + bytes + 255) & ~(size_t)255; return p; };
    bf16_t* skipb = (bf16_t*)alloc((size_t)Mpad * 32 * 2);
    bf16_t* WbfT  = (bf16_t*)alloc(256 * 288 * 2);
    bf16_t* WqT   = (bf16_t*)alloc(128 * 384 * 2);
    float*  bpn   = (float*)alloc(256 * 4);
    float*  bpq   = (float*)alloc(128 * 4);
    bf16_t* KVb   = (bf16_t*)alloc((size_t)Mpad * 256 * 2);
    bf16_t* Qb    = (bf16_t*)alloc((size_t)Mq * 128 * 2);
    // cnt and cur MUST be contiguous: prep_all zeroes cnt[0..2P)
    int*    cnt   = (int*)alloc((size_t)(2 * P) * 4);
    int*    cur   = cnt + P;
    int*    offb  = (int*)alloc((size_t)(P + 1) * 4);
    int*    csrc  = (int*)alloc((size_t)E * 4);
    bf16_t* AG    = (bf16_t*)alloc((size_t)Mq * 256 * 2);
    bf16_t* BTg   = (bf16_t*)alloc(512 * 256 * 2);
    bf16_t* W1Tp  = (bf16_t*)alloc(128 * 128 * 2);
    bf16_t* W2Tp  = (bf16_t*)alloc(128 * 128 * 2);
    float*  bgru  = (float*)alloc(512 * 4);
    float*  b1p   = (float*)alloc(128 * 4);
    float*  G512  = (float*)alloc((size_t)Mq * 512 * 4);
    bf16_t* LNb   = (bf16_t*)alloc((size_t)Mq * 128 * 2);
    bf16_t* M1    = (bf16_t*)alloc((size_t)Mq * 128 * 2);

    // 1. merged weight prep (+ cnt zero + AG pad zero) + skip features
    {
        int padElems = (Mq - P) * 256;
        int T1 = 256 * 288 + 128 * 384 + 256 + 128;
        int T2 = 512 * 256 + 128 * 128 + 128 * 128 + 512 + 128 + 2 * P + padElems;
        prep_all<<<(T1 + T2 + THREADS - 1) / THREADS, THREADS, 0, stream>>>(
            W_key, W_val, W_q, b_key, b_val, b_q, WbfT, WqT, bpn, bpq,
            W_ih, W_hh, b_ih, b_hh, W1, b1, W2, BTg, W1Tp, W2Tp, bgru, b1p,
            cnt, 2 * P, AG, P, padElems);
        skip_kernel<<<(Mpad + THREADS - 1) / THREADS, THREADS, 0, stream>>>(
            energy, eta, phi, layer, eta_l, phi_l, ene_l, track, skipb, N, Mpad);
    }
    // 2. K/V GEMM (BN=256, single A pass) + Q GEMM
    kv_gemm512<<<Mpad / 64, 512, 0, stream>>>(nh, skipb, WbfT, bpn, KVb, N);
    mfma_gemm<1><<<dim3(1, Mq / 64), THREADS, 0, stream>>>(
        ph, grep, WqT, bpq, Qb, nullptr, 384, 0, P);
    // 3. CSR build (src ids stored directly)
    hist_kernel<<<(E + THREADS - 1) / THREADS, THREADS, 0, stream>>>(edst, cnt, E);
    scan_kernel<<<1, 1024, 0, stream>>>(cnt, offb, P);
    fill_src_kernel<<<(E + THREADS - 1) / THREADS, THREADS, 0, stream>>>(
        edst, esrc, offb, cur, csrc, E);
    // 4. fused attention + gather + gate -> AG
    edge_kernel<<<(P + 3) / 4, THREADS, 0, stream>>>(
        offb, csrc, KVb, Qb, ph, rms_w, lin_w, AG, P);
    // 5. node update: GRU GEMM (512 cols, r/z folded) -> pointwise+LN -> MLP
    mfma_gemm<2><<<dim3(4, Mq / 64), THREADS, 0, stream>>>(
        AG, nullptr, BTg, bgru, G512, nullptr, 256, 0, Mq);
    gru_ln_kernel<<<Mq / 16, THREADS, 0, stream>>>(G512, ph, ln_g, ln_b, LNb, P, Mq);
    mfma_gemm<3><<<dim3(1, Mq / 64), THREADS, 0, stream>>>(
        LNb, nullptr, W1Tp, b1p, M1, nullptr, 128, 0, Mq);
    mfma_gemm<4><<<dim3(1, Mq / 64), THREADS, 0, stream>>>(
        M1, nullptr, W2Tp, b2, d_out, ph, 128, P, Mq);
}